// Round 10
// baseline (624.603 us; speedup 1.0000x reference)
//
#include <hip/hip_runtime.h>
#include <stdint.h>

#define NIMG 512
#define CINCH 64
#define HIDC 128
#define NEDGE 16384
#define HWPIX 1024
#define PW2 34
#define PPIX 1156   // 34*34
#define APITCH 272  // LDS A-tile pixel pitch (16 chunks + 1 dead)
#define AROW 9248   // 34*272

typedef __attribute__((ext_vector_type(8))) short bf16x8;
typedef __attribute__((ext_vector_type(4))) float f32x4;
typedef __attribute__((ext_vector_type(16))) float f32x16;

static __device__ __forceinline__ unsigned short f2bf(float f){
  unsigned u = __builtin_bit_cast(unsigned, f);
  u += 0x7FFFu + ((u>>16)&1u);
  return (unsigned short)(u>>16);
}
static __device__ __forceinline__ float bf2f(unsigned short s){
  unsigned u = ((unsigned)s)<<16;
  return __builtin_bit_cast(float, u);
}

// async 16B global->LDS, LDS side linear per wave (m104)
static __device__ __forceinline__ void gload16(const char* src, char* dst){
  __builtin_amdgcn_global_load_lds(
      (const __attribute__((address_space(1))) unsigned int*)src,
      (__attribute__((address_space(3))) unsigned int*)dst, 16, 0, 0);
}

// ---------------- init: zero pad borders + accumulators + csr counters ------
__global__ void k_init(unsigned short* xe_pad, unsigned short* xp1_pad,
                       float* xnode_acc, int* cnt, int* pos){
  int idx = blockIdx.x*256 + threadIdx.x;
  int total_b = NIMG*132*16;
  for(int i = idx; i < total_b; i += gridDim.x*256){
    int img = i / (132*16);
    int rem = i - img*(132*16);
    int bp = rem >> 4;
    int slot = rem & 15;
    int r, c;
    if(bp < 34){ r = 0; c = bp; }
    else if(bp < 68){ r = 33; c = bp-34; }
    else if(bp < 100){ r = bp-68+1; c = 0; }
    else { r = bp-100+1; c = 33; }
    size_t off = ((size_t)img*PPIX + r*PW2 + c)*128 + slot*8;
    uint4 z = {0,0,0,0};
    *(uint4*)(xe_pad + off) = z;
    *(uint4*)(xp1_pad + off) = z;
  }
  for(int i = idx; i < NIMG*HIDC; i += gridDim.x*256) xnode_acc[i] = 0.f;
  for(int i = idx; i < NIMG; i += gridDim.x*256){ cnt[i] = 0; pos[i] = 0; }
}

// ---------------- weight conversion ------------------------------------------
// conv3 W image: [tap][co][slot 0..15][8] bf16; slot holds cin-group (slot-3co)&15.
__global__ void k_wconv(const float* __restrict__ sp_w1, const float* __restrict__ sp_w2,
                        const float* __restrict__ fe_w, const float* __restrict__ op_w,
                        unsigned short* Wb1, unsigned short* Wb2,
                        unsigned short* Wfe, unsigned short* Wop){
  int idx = blockIdx.x*256 + threadIdx.x;
  for(int i = idx; i < 147456; i += gridDim.x*256){
    int j = i & 7, slot = (i>>3)&15, co = (i>>7)&127, tap = i>>14;
    int cin = (((slot - 3*co) & 15)<<3) + j;
    Wb1[i] = f2bf(sp_w1[(co*128+cin)*9 + tap]);
    Wb2[i] = f2bf(sp_w2[(co*128+cin)*9 + tap]);
  }
  for(int i = idx; i < 8192; i += gridDim.x*256){
    int j = i & 7, s = (i>>3)&7, co = i>>6;
    int ci = ((s ^ (co&7))<<3) + j;
    Wfe[i] = f2bf(fe_w[co*64+ci]);
  }
  for(int i = idx; i < 8192; i += gridDim.x*256){
    int j = i & 7, s = (i>>3)&15, co = i>>7;   // co 0..63
    int cin = ((s ^ (co&7))<<3) + j;
    Wop[i] = f2bf(op_w[co*128+cin]);
  }
}

// ---------------- CSR build ------------------------------------------------
__global__ void k_csr_count(const int* __restrict__ ei, int* cnt){
  int e = blockIdx.x*256 + threadIdx.x;
  if(e < NEDGE) atomicAdd(&cnt[ei[NEDGE+e]], 1);
}
__global__ void k_csr_scan(const int* __restrict__ cnt, int* offs){
  __shared__ int sc[512];
  int t = threadIdx.x;
  sc[t] = cnt[t] + 1;   // +1 for self loop
  __syncthreads();
  for(int o = 1; o < 512; o <<= 1){
    int add = (t >= o) ? sc[t-o] : 0;
    __syncthreads();
    sc[t] += add;
    __syncthreads();
  }
  if(t == 0) offs[0] = 0;
  offs[t+1] = sc[t];
}
__global__ void k_csr_fill(const int* __restrict__ ei, const int* __restrict__ offs,
                           int* pos, int* csr_src){
  int e = blockIdx.x*256 + threadIdx.x;
  if(e < NEDGE + NIMG){
    int s, d;
    if(e < NEDGE){ s = ei[e]; d = ei[NEDGE+e]; }
    else { s = e - NEDGE; d = s; }
    int slot = offs[d] + atomicAdd(&pos[d], 1);
    csr_src[slot] = s;
  }
}

// ---------------- encode: 1x1 conv + BN + relu + conf, padded NHWC (baked) --
__launch_bounds__(256, 2)
__global__ void k_encode(const float* __restrict__ x, const float* __restrict__ conf,
                         const unsigned short* __restrict__ Wfe,
                         const float* __restrict__ fe_b, const float* __restrict__ fe_g,
                         const float* __restrict__ fe_beta,
                         unsigned short* __restrict__ xe_pad){
  __shared__ char lds[49152];          // xa 32KB (f32 swizzled) + wb 16KB
  char* xa = lds; char* wb = lds + 32768;
  int tid = threadIdx.x;
  int n = blockIdx.x >> 3, rg = blockIdx.x & 7;
  int hw0 = rg*128;
  {
    int q = tid >> 3, c0 = tid & 7;
    const float* xb = x + (size_t)n*CINCH*HWPIX + hw0;
    #pragma unroll
    for(int cc = 0; cc < 8; ++cc){
      int c = cc*8 + c0;
      float4 v = *(const float4*)(xb + (size_t)c*HWPIX + q*4);
      float vv[4] = {v.x, v.y, v.z, v.w};
      #pragma unroll
      for(int i = 0; i < 4; ++i){
        int p = q*4 + i;
        *(float*)(xa + p*256 + ((cc ^ (p&7))*32) + c0*4) = vv[i];
      }
    }
    #pragma unroll
    for(int it = 0; it < 4; ++it){
      uint4 w = *(const uint4*)((const char*)Wfe + it*4096 + tid*16);
      *(uint4*)(wb + it*4096 + tid*16) = w;
    }
  }
  __syncthreads();
  int wid = tid>>6, lane = tid&63;
  int wr = wid>>1, wc = wid&1, fr = lane&15, fq = lane>>4;
  f32x4 acc[4][4];
  #pragma unroll
  for(int a = 0; a < 4; ++a)
    #pragma unroll
    for(int b = 0; b < 4; ++b) acc[a][b] = (f32x4){0.f,0.f,0.f,0.f};
  #pragma unroll
  for(int kc = 0; kc < 2; ++kc){
    bf16x8 af[4], bfr[4];
    #pragma unroll
    for(int mi = 0; mi < 4; ++mi){
      int p = wr*64 + mi*16 + fr;
      int u = kc*4 + fq;
      const float* src = (const float*)(xa + p*256 + ((u ^ (p&7))*32));
      float4 lo = *(const float4*)src;
      float4 hi = *(const float4*)(src+4);
      bf16x8 a;
      a[0]=(short)f2bf(lo.x); a[1]=(short)f2bf(lo.y); a[2]=(short)f2bf(lo.z); a[3]=(short)f2bf(lo.w);
      a[4]=(short)f2bf(hi.x); a[5]=(short)f2bf(hi.y); a[6]=(short)f2bf(hi.z); a[7]=(short)f2bf(hi.w);
      af[mi] = a;
    }
    #pragma unroll
    for(int nf = 0; nf < 4; ++nf){
      int co = wc*64 + nf*16 + fr;
      int slot = (kc*4 + fq) ^ (co&7);
      bfr[nf] = *(const bf16x8*)(wb + co*128 + slot*16);
    }
    #pragma unroll
    for(int mi = 0; mi < 4; ++mi)
      #pragma unroll
      for(int nf = 0; nf < 4; ++nf)
        acc[mi][nf] = __builtin_amdgcn_mfma_f32_16x16x32_bf16(af[mi], bfr[nf], acc[mi][nf], 0,0,0);
  }
  __syncthreads();
  {
    const float rs = 0.9999950000374997f;
    float kb[4], ks[4], kbe[4];
    #pragma unroll
    for(int nf = 0; nf < 4; ++nf){
      int co = wc*64 + nf*16 + fr;
      kb[nf] = fe_b[co]; ks[nf] = fe_g[co]*rs; kbe[nf] = fe_beta[co];
    }
    #pragma unroll
    for(int mi = 0; mi < 4; ++mi)
      #pragma unroll
      for(int j = 0; j < 4; ++j){
        int px = wr*64 + mi*16 + fq*4 + j;
        float cf = conf[(size_t)n*HWPIX + hw0 + px];
        #pragma unroll
        for(int nf = 0; nf < 4; ++nf){
          float v = (acc[mi][nf][j] + kb[nf])*ks[nf] + kbe[nf];
          v = fmaxf(v, 0.f)*cf;
          int co = wc*64 + nf*16 + fr;
          *(unsigned short*)(xa + px*256 + ((co*2) ^ (((px>>2)&7)<<4))) = f2bf(v);
        }
      }
  }
  __syncthreads();
  {
    int p = tid>>1, half = tid&1;
    int r = rg*4 + (p>>5), c = p&31;
    int key = 2*((p&31) + 1);                // additive key, padded col
    unsigned short* dst = xe_pad + ((size_t)n*PPIX + (r+1)*PW2 + (c+1))*128;
    #pragma unroll
    for(int s = 0; s < 8; ++s){
      int ls = half*8 + s;
      uint4 v = *(uint4*)(xa + p*256 + ((ls*16) ^ (((p>>2)&7)<<4)));
      *(uint4*)(dst + ((ls + key)&15)*8) = v;
    }
  }
}

// ---------------- 3x3 conv: 4 waves, wave tile 128px x 64co, 32x32x16 MFMA --
// acc[4][2] f32x16 (128 VGPR): 8 independent MFMA per kc-step, 6 ds_reads
// (0.75 reads/MFMA). Layouts identical to R9 (conflict-free baked swizzles).
// A tile staged once; W per-tap double-buffered via linear gload_lds.
__launch_bounds__(256, 1)
__global__ void k_conv3(const unsigned short* __restrict__ inp,   // padded, baked
                        const unsigned short* __restrict__ Wb,    // [9][128][16][8] baked
                        const float* __restrict__ bnb, const float* __restrict__ bng,
                        const float* __restrict__ bnbe,
                        unsigned short* __restrict__ outp,
                        float* __restrict__ xnode_acc, int mode){
  extern __shared__ char lds[];
  char* Ab = lds;                 // 93184 (5824 granules; >=5780 used)
  char* Wd = lds + 93184;         // 2 x 32768
  int tid = threadIdx.x;
  int n = blockIdx.x>>2, rg = blockIdx.x&3;

  const char* img  = (const char*)inp + ((size_t)n*PPIX + (size_t)rg*8*PW2)*256;
  const char* wsrc = (const char*)Wb;

  // prologue: stage W tap0 + A tile (272-pitch LDS, 256-pitch global)
  #pragma unroll
  for(int it = 0; it < 8; ++it)
    gload16(wsrc + it*4096 + tid*16, Wd + it*4096 + tid*16);
  #pragma unroll
  for(int it = 0; it < 23; ++it){
    int j = tid + it*256;
    if(it < 22 || j < 5824){          // tail = 192 threads = 3 FULL waves
      int pidx = j/17, s = j - pidx*17;
      if(pidx > 339) pidx = 339;      // clamp: dead region, never read
      if(s == 16) s = 0;              // dead slot: dup-load keeps lane active
      gload16(img + (size_t)pidx*256 + s*16, Ab + (size_t)j*16);
    }
  }

  int wid = tid>>6, lane = tid&63;
  int wr = wid>>1, wc = wid&1;                 // wr 0..1 (4-row group), wc 0..1
  int col = lane&31, hi = lane>>5;
  int cob = (wc*64 + col)*256;                 // nf=0 W row base

  f32x16 acc[4][2];
  #pragma unroll
  for(int a = 0; a < 4; ++a)
    #pragma unroll
    for(int b = 0; b < 2; ++b)
      #pragma unroll
      for(int r = 0; r < 16; ++r) acc[a][b][r] = 0.f;

  __syncthreads();

  for(int tap = 0; tap < 9; ++tap){
    if(tap < 8){
      const char* ws = wsrc + (size_t)(tap+1)*32768;
      char* wdst = Wd + ((tap+1)&1)*32768;
      #pragma unroll
      for(int it = 0; it < 8; ++it)
        gload16(ws + it*4096 + tid*16, wdst + it*4096 + tid*16);
    }
    const char* cur = Wd + (tap&1)*32768;
    int dy = tap/3 - 1, dx = tap - (tap/3)*3 - 1;
    int pcol = col + 1 + dx;
    int prow0 = wr*4 + 1 + dy;                  // mi=0 sample row (0..9 range)
    int a0 = prow0*AROW + pcol*APITCH;
    int ka = 2*pcol;                            // additive A slot key (col-only)
    #pragma unroll
    for(int kc = 0; kc < 8; ++kc){
      int g = kc*2 + hi;
      int sa = ((g + ka)&15)<<4;
      bf16x8 af0 = *(const bf16x8*)(Ab + a0 + sa);
      bf16x8 af1 = *(const bf16x8*)(Ab + a0 + AROW + sa);
      bf16x8 af2 = *(const bf16x8*)(Ab + a0 + 2*AROW + sa);
      bf16x8 af3 = *(const bf16x8*)(Ab + a0 + 3*AROW + sa);
      int sw = ((g + 3*col)&15)<<4;
      bf16x8 wf0 = *(const bf16x8*)(cur + cob + sw);
      bf16x8 wf1 = *(const bf16x8*)(cur + cob + 8192 + sw);   // nf=1: +32co
      acc[0][0] = __builtin_amdgcn_mfma_f32_32x32x16_bf16(af0, wf0, acc[0][0], 0,0,0);
      acc[0][1] = __builtin_amdgcn_mfma_f32_32x32x16_bf16(af0, wf1, acc[0][1], 0,0,0);
      acc[1][0] = __builtin_amdgcn_mfma_f32_32x32x16_bf16(af1, wf0, acc[1][0], 0,0,0);
      acc[1][1] = __builtin_amdgcn_mfma_f32_32x32x16_bf16(af1, wf1, acc[1][1], 0,0,0);
      acc[2][0] = __builtin_amdgcn_mfma_f32_32x32x16_bf16(af2, wf0, acc[2][0], 0,0,0);
      acc[2][1] = __builtin_amdgcn_mfma_f32_32x32x16_bf16(af2, wf1, acc[2][1], 0,0,0);
      acc[3][0] = __builtin_amdgcn_mfma_f32_32x32x16_bf16(af3, wf0, acc[3][0], 0,0,0);
      acc[3][1] = __builtin_amdgcn_mfma_f32_32x32x16_bf16(af3, wf1, acc[3][1], 0,0,0);
    }
    __syncthreads();   // all reads of cur done + next stage landed (vmcnt drain)
  }

  // epilogue: BN + relu -> LDS transpose scratch (reuse A region), xnode regs
  char* eb = Ab;
  float sn0 = 0.f, sn1 = 0.f;
  {
    const float rs = 0.9999950000374997f;
    float kb[2], ks[2], kbe[2];
    #pragma unroll
    for(int nf = 0; nf < 2; ++nf){
      int co = wc*64 + nf*32 + col;
      kb[nf] = bnb[co]; ks[nf] = bng[co]*rs; kbe[nf] = bnbe[co];
    }
    #pragma unroll
    for(int mi = 0; mi < 4; ++mi)
      #pragma unroll
      for(int reg = 0; reg < 16; ++reg){
        int pc = (reg&3) + 8*(reg>>2) + 4*hi;
        int px = (wr*4 + mi)*32 + pc;           // block-local 0..255
        #pragma unroll
        for(int nf = 0; nf < 2; ++nf){
          float v = (acc[mi][nf][reg] + kb[nf])*ks[nf] + kbe[nf];
          v = fmaxf(v, 0.f);
          if(nf == 0) sn0 += v; else sn1 += v;
          int co = wc*64 + nf*32 + col;
          *(unsigned short*)(eb + px*256 + ((co*2) ^ (((px>>2)&7)<<4))) = f2bf(v);
        }
      }
  }
  if(mode == 1){
    sn0 += __shfl_down(sn0, 32);
    sn1 += __shfl_down(sn1, 32);
    if(lane < 32){
      atomicAdd(&xnode_acc[n*HIDC + wc*64 + col], sn0);
      atomicAdd(&xnode_acc[n*HIDC + wc*64 + 32 + col], sn1);
    }
  }
  __syncthreads();
  {
    int p = tid;                                 // p 0..255, one px per thread
    int r = rg*8 + (p>>5), c = p&31;
    unsigned short* dst;
    int key;
    if(mode == 0){
      key = 2*((p&31) + 1);                     // padded additive key
      dst = outp + ((size_t)n*PPIX + (r+1)*PW2 + (c+1))*128;
    } else {
      key = 3*p;                                 // flat additive key (3*hw mod 16)
      dst = outp + ((size_t)n*HWPIX + rg*256 + p)*128;
    }
    #pragma unroll
    for(int s = 0; s < 16; ++s){
      uint4 v = *(uint4*)(eb + p*256 + ((s*16) ^ (((p>>2)&7)<<4)));
      *(uint4*)(dst + ((s + key)&15)*8) = v;
    }
  }
}

// ---------------- GAT linear: h = x@lin, plus per-head attn dots ------------
__global__ void k_gat_lin(const float* __restrict__ xin, float scale,
                          const float* __restrict__ lin,
                          const float* __restrict__ as_, const float* __restrict__ ad_,
                          float* __restrict__ h, float* __restrict__ a_s, float* __restrict__ a_d){
  __shared__ float xs[128];
  __shared__ float rs0[4], rs1[4], rd0[4], rd1[4];
  int n = blockIdx.x, t = threadIdx.x;
  if(t < 128) xs[t] = xin[n*128 + t]*scale;
  __syncthreads();
  float o0 = 0.f, o1 = 0.f;
  for(int k = 0; k < 128; ++k){
    float xv = xs[k];
    o0 += xv*lin[k*512 + t];
    o1 += xv*lin[k*512 + t + 256];
  }
  h[(size_t)n*512 + t] = o0;
  h[(size_t)n*512 + t + 256] = o1;
  float s0 = o0*as_[t], s1 = o1*as_[t+256];
  float d0 = o0*ad_[t], d1 = o1*ad_[t+256];
  #pragma unroll
  for(int o = 32; o; o >>= 1){
    s0 += __shfl_down(s0, o); s1 += __shfl_down(s1, o);
    d0 += __shfl_down(d0, o); d1 += __shfl_down(d1, o);
  }
  int w = t>>6;
  if((t&63) == 0){ rs0[w]=s0; rs1[w]=s1; rd0[w]=d0; rd1[w]=d1; }
  __syncthreads();
  if(t < 4){
    if(t < 2){
      a_s[n*4+t] = rs0[2*t] + rs0[2*t+1];
      a_d[n*4+t] = rd0[2*t] + rd0[2*t+1];
    } else {
      a_s[n*4+t] = rs1[2*(t-2)] + rs1[2*(t-2)+1];
      a_d[n*4+t] = rd1[2*(t-2)] + rd1[2*(t-2)+1];
    }
  }
}

// ---------------- GAT aggregate: per-dst softmax + weighted sum -------------
__global__ void k_gat_aggr(const int* __restrict__ offs, const int* __restrict__ csr_src,
                           const float* __restrict__ a_s, const float* __restrict__ a_d,
                           const float* __restrict__ h, const float* __restrict__ bias,
                           float* __restrict__ y){
  __shared__ int ssrc[2048];
  __shared__ float sex[4][2048];
  __shared__ float out4[512];
  __shared__ float adn[4], smax[4], sden[4];
  __shared__ float wred[4][4];
  int n = blockIdx.x, t = threadIdx.x;
  int base = offs[n], deg = offs[n+1] - base;
  if(t < 4) adn[t] = a_d[n*4 + t];
  __syncthreads();
  bool cached = (deg <= 2048);
  float lm0=-1e30f, lm1=-1e30f, lm2=-1e30f, lm3=-1e30f;
  for(int e = t; e < deg; e += 256){
    int s = csr_src[base + e];
    float v0 = a_s[s*4+0] + adn[0]; v0 = v0 > 0.f ? v0 : 0.2f*v0;
    float v1 = a_s[s*4+1] + adn[1]; v1 = v1 > 0.f ? v1 : 0.2f*v1;
    float v2 = a_s[s*4+2] + adn[2]; v2 = v2 > 0.f ? v2 : 0.2f*v2;
    float v3 = a_s[s*4+3] + adn[3]; v3 = v3 > 0.f ? v3 : 0.2f*v3;
    if(cached){ ssrc[e]=s; sex[0][e]=v0; sex[1][e]=v1; sex[2][e]=v2; sex[3][e]=v3; }
    lm0 = fmaxf(lm0, v0); lm1 = fmaxf(lm1, v1); lm2 = fmaxf(lm2, v2); lm3 = fmaxf(lm3, v3);
  }
  #pragma unroll
  for(int o = 32; o; o >>= 1){
    lm0 = fmaxf(lm0, __shfl_down(lm0, o)); lm1 = fmaxf(lm1, __shfl_down(lm1, o));
    lm2 = fmaxf(lm2, __shfl_down(lm2, o)); lm3 = fmaxf(lm3, __shfl_down(lm3, o));
  }
  int w = t>>6;
  if((t&63) == 0){ wred[w][0]=lm0; wred[w][1]=lm1; wred[w][2]=lm2; wred[w][3]=lm3; }
  __syncthreads();
  if(t < 4) smax[t] = fmaxf(fmaxf(wred[0][t], wred[1][t]), fmaxf(wred[2][t], wred[3][t]));
  __syncthreads();
  float m0 = smax[0], m1 = smax[1], m2 = smax[2], m3 = smax[3];
  float ls0=0.f, ls1=0.f, ls2=0.f, ls3=0.f;
  for(int e = t; e < deg; e += 256){
    float e0, e1, e2, e3;
    if(cached){ e0 = sex[0][e]; e1 = sex[1][e]; e2 = sex[2][e]; e3 = sex[3][e]; }
    else {
      int s = csr_src[base + e];
      e0 = a_s[s*4+0] + adn[0]; e0 = e0 > 0.f ? e0 : 0.2f*e0;
      e1 = a_s[s*4+1] + adn[1]; e1 = e1 > 0.f ? e1 : 0.2f*e1;
      e2 = a_s[s*4+2] + adn[2]; e2 = e2 > 0.f ? e2 : 0.2f*e2;
      e3 = a_s[s*4+3] + adn[3]; e3 = e3 > 0.f ? e3 : 0.2f*e3;
    }
    e0 = __expf(e0-m0); e1 = __expf(e1-m1); e2 = __expf(e2-m2); e3 = __expf(e3-m3);
    if(cached){ sex[0][e]=e0; sex[1][e]=e1; sex[2][e]=e2; sex[3][e]=e3; }
    ls0 += e0; ls1 += e1; ls2 += e2; ls3 += e3;
  }
  #pragma unroll
  for(int o = 32; o; o >>= 1){
    ls0 += __shfl_down(ls0, o); ls1 += __shfl_down(ls1, o);
    ls2 += __shfl_down(ls2, o); ls3 += __shfl_down(ls3, o);
  }
  __syncthreads();   // wred(max) fully consumed
  if((t&63) == 0){ wred[w][0]=ls0; wred[w][1]=ls1; wred[w][2]=ls2; wred[w][3]=ls3; }
  __syncthreads();
  if(t < 4) sden[t] = wred[0][t] + wred[1][t] + wred[2][t] + wred[3][t] + 1e-16f;
  __syncthreads();
  #pragma unroll
  for(int oo = 0; oo < 2; ++oo){
    int o = t + oo*256;
    int hd = o>>7, d = o&127;
    float mh = smax[hd];
    float accv = 0.f;
    for(int e = 0; e < deg; ++e){
      float ex; int s;
      if(cached){ ex = sex[hd][e]; s = ssrc[e]; }
      else {
        s = csr_src[base + e];
        float v = a_s[s*4+hd] + adn[hd]; v = v > 0.f ? v : 0.2f*v;
        ex = __expf(v - mh);
      }
      accv += ex * h[(size_t)s*512 + hd*128 + d];
    }
    out4[o] = accv / sden[hd];
  }
  __syncthreads();
  if(t < 128){
    float v = (out4[t] + out4[128+t] + out4[256+t] + out4[384+t])*0.25f + bias[t];
    y[n*128 + t] = fmaxf(v, 0.f);
  }
}

// ---------------- per-node bias for final conv: nb = op_w @ xg2 + op_b ------
__global__ void k_nodebias(const float* __restrict__ xg2, const float* __restrict__ op_w,
                           const float* __restrict__ op_b, float* __restrict__ nb){
  int g = blockIdx.x*256 + threadIdx.x;
  if(g < NIMG*64){
    int n = g>>6, co = g&63;
    float acc = op_b[co];
    for(int k = 0; k < 128; ++k) acc += op_w[co*128+k]*xg2[n*128+k];
    nb[g] = acc;
  }
}

// ---------------- final 1x1 conv: out = op_w@xp2 + nb, NCHW f32 -------------
__launch_bounds__(256, 2)
__global__ void k_outconv(const unsigned short* __restrict__ xp2,  // flat, slot=(g+3hw)&15
                          const unsigned short* __restrict__ Wop,
                          const float* __restrict__ nb, float* __restrict__ out){
  __shared__ char lds[16384];
  int tid = threadIdx.x;
  int n = blockIdx.x>>3, rg = blockIdx.x&7;
  #pragma unroll
  for(int it = 0; it < 4; ++it){
    uint4 v = *(const uint4*)((const char*)Wop + it*4096 + tid*16);
    *(uint4*)(lds + it*4096 + tid*16) = v;
  }
  __syncthreads();
  int wid = tid>>6, lane = tid&63;
  int wr = wid>>1, wc = wid&1, fr = lane&15, fq = lane>>4;
  f32x4 acc[4][2];
  #pragma unroll
  for(int a = 0; a < 4; ++a){ acc[a][0] = (f32x4){0.f,0.f,0.f,0.f}; acc[a][1] = (f32x4){0.f,0.f,0.f,0.f}; }
  const unsigned short* abase = xp2 + ((size_t)n*HWPIX + rg*128)*128;
  #pragma unroll
  for(int kc = 0; kc < 4; ++kc){
    bf16x8 af[4], bfr[2];
    #pragma unroll
    for(int mi = 0; mi < 4; ++mi){
      int p = wr*64 + mi*16 + fr;
      af[mi] = *(const bf16x8*)(abase + p*128 + (((kc*4+fq) + 3*p)&15)*8);
    }
    #pragma unroll
    for(int nf = 0; nf < 2; ++nf){
      int co = wc*32 + nf*16 + fr;
      int slot = (kc*4 + fq) ^ (co&7);
      bfr[nf] = *(const bf16x8*)(lds + co*256 + slot*16);
    }
    #pragma unroll
    for(int mi = 0; mi < 4; ++mi)
      #pragma unroll
      for(int nf = 0; nf < 2; ++nf)
        acc[mi][nf] = __builtin_amdgcn_mfma_f32_16x16x32_bf16(af[mi], bfr[nf], acc[mi][nf], 0,0,0);
  }
  #pragma unroll
  for(int mi = 0; mi < 4; ++mi)
    #pragma unroll
    for(int nf = 0; nf < 2; ++nf){
      int co = wc*32 + nf*16 + fr;
      int hw = rg*128 + wr*64 + mi*16 + fq*4;
      float nbv = nb[n*64 + co];
      float4 v = { acc[mi][nf][0]+nbv, acc[mi][nf][1]+nbv, acc[mi][nf][2]+nbv, acc[mi][nf][3]+nbv };
      *(float4*)(out + ((size_t)n*64 + co)*HWPIX + hw) = v;
    }
}

// ---------------- host launch ----------------------------------------------
extern "C" void kernel_launch(void* const* d_in, const int* in_sizes, int n_in,
                              void* d_out, int out_size, void* d_ws, size_t ws_size,
                              hipStream_t stream){
  const float* x       = (const float*)d_in[0];
  const int*   ei      = (const int*)d_in[1];
  const float* conf    = (const float*)d_in[2];
  const float* fe_w    = (const float*)d_in[3];
  const float* fe_b    = (const float*)d_in[4];
  const float* fe_g    = (const float*)d_in[5];
  const float* fe_beta = (const float*)d_in[6];
  const float* sp_w1   = (const float*)d_in[7];
  const float* sp_b1   = (const float*)d_in[8];
  const float* sp_g1   = (const float*)d_in[9];
  const float* sp_be1  = (const float*)d_in[10];
  const float* sp_w2   = (const float*)d_in[11];
  const float* sp_b2   = (const float*)d_in[12];
  const float* sp_g2   = (const float*)d_in[13];
  const float* sp_be2  = (const float*)d_in[14];
  const float* g1_lin  = (const float*)d_in[15];
  const float* g1_as   = (const float*)d_in[16];
  const float* g1_ad   = (const float*)d_in[17];
  const float* g1_b    = (const float*)d_in[18];
  const float* g2_lin  = (const float*)d_in[19];
  const float* g2_as   = (const float*)d_in[20];
  const float* g2_ad   = (const float*)d_in[21];
  const float* g2_b    = (const float*)d_in[22];
  const float* op_w    = (const float*)d_in[23];
  const float* op_b    = (const float*)d_in[24];
  float* out = (float*)d_out;

  char* ws = (char*)d_ws;
  size_t off = 0;
  auto alloc = [&](size_t bytes)->char*{
    char* p = ws + off; off += (bytes + 255) & ~(size_t)255; return p;
  };
  unsigned short* bigA  = (unsigned short*)alloc((size_t)NIMG*PPIX*128*2); // xe_pad, later xp2
  unsigned short* xp1   = (unsigned short*)alloc((size_t)NIMG*PPIX*128*2);
  unsigned short* Wb1   = (unsigned short*)alloc(147456*2);
  unsigned short* Wb2   = (unsigned short*)alloc(147456*2);
  unsigned short* Wfe   = (unsigned short*)alloc(8192*2);
  unsigned short* Wop   = (unsigned short*)alloc(8192*2);
  float* xnode_acc = (float*)alloc(NIMG*HIDC*4);
  float* h     = (float*)alloc((size_t)NIMG*512*4);
  float* a_s   = (float*)alloc(NIMG*4*4);
  float* a_d   = (float*)alloc(NIMG*4*4);
  float* xg1   = (float*)alloc(NIMG*HIDC*4);
  float* xg2   = (float*)alloc(NIMG*HIDC*4);
  int* cnt     = (int*)alloc(NIMG*4);
  int* pos     = (int*)alloc(NIMG*4);
  int* offs    = (int*)alloc((NIMG+1)*4);
  int* csr_src = (int*)alloc((NEDGE+NIMG)*4);
  float* nb    = (float*)alloc(NIMG*64*4);
  if(off > ws_size) return;   // workspace too small — bail cleanly
  unsigned short* xp2 = bigA; // reuse region A after conv1 consumed xe

  // 158720 B dynamic LDS for k_conv3 (A 93184 + W dbuf 65536); 1 block/CU.
  hipFuncSetAttribute((const void*)k_conv3,
                      hipFuncAttributeMaxDynamicSharedMemorySize, 158720);

  k_init<<<1024, 256, 0, stream>>>(bigA, xp1, xnode_acc, cnt, pos);
  k_wconv<<<576, 256, 0, stream>>>(sp_w1, sp_w2, fe_w, op_w, Wb1, Wb2, Wfe, Wop);
  k_csr_count<<<(NEDGE+255)/256, 256, 0, stream>>>(ei, cnt);
  k_csr_scan<<<1, 512, 0, stream>>>(cnt, offs);
  k_csr_fill<<<(NEDGE+NIMG+255)/256, 256, 0, stream>>>(ei, offs, pos, csr_src);
  k_encode<<<4096, 256, 0, stream>>>(x, conf, Wfe, fe_b, fe_g, fe_beta, bigA);
  k_conv3<<<2048, 256, 158720, stream>>>(bigA, Wb1, sp_b1, sp_g1, sp_be1, xp1, xnode_acc, 0);
  k_conv3<<<2048, 256, 158720, stream>>>(xp1, Wb2, sp_b2, sp_g2, sp_be2, xp2, xnode_acc, 1);
  k_gat_lin<<<512, 256, 0, stream>>>(xnode_acc, 1.f/1024.f, g1_lin, g1_as, g1_ad, h, a_s, a_d);
  k_gat_aggr<<<512, 256, 0, stream>>>(offs, csr_src, a_s, a_d, h, g1_b, xg1);
  k_gat_lin<<<512, 256, 0, stream>>>(xg1, 1.f, g2_lin, g2_as, g2_ad, h, a_s, a_d);
  k_gat_aggr<<<512, 256, 0, stream>>>(offs, csr_src, a_s, a_d, h, g2_b, xg2);
  k_nodebias<<<(NIMG*64+255)/256, 256, 0, stream>>>(xg2, op_w, op_b, nb);
  k_outconv<<<4096, 256, 0, stream>>>(xp2, Wop, nb, out);
}

// Round 11
// 604.876 us; speedup vs baseline: 1.0326x; 1.0326x over previous
//
#include <hip/hip_runtime.h>
#include <stdint.h>

#define NIMG 512
#define CINCH 64
#define HIDC 128
#define NEDGE 16384
#define HWPIX 1024
#define PW2 34
#define PPIX 1156   // 34*34
#define APITCH 272  // LDS A-tile pixel pitch (16 chunks + 1 dead)
#define AROW 9248   // 34*272

typedef __attribute__((ext_vector_type(8))) short bf16x8;
typedef __attribute__((ext_vector_type(4))) float f32x4;
typedef __attribute__((ext_vector_type(16))) float f32x16;

static __device__ __forceinline__ unsigned short f2bf(float f){
  unsigned u = __builtin_bit_cast(unsigned, f);
  u += 0x7FFFu + ((u>>16)&1u);
  return (unsigned short)(u>>16);
}
static __device__ __forceinline__ float bf2f(unsigned short s){
  unsigned u = ((unsigned)s)<<16;
  return __builtin_bit_cast(float, u);
}

// async 16B global->LDS, LDS side linear per wave (m104)
static __device__ __forceinline__ void gload16(const char* src, char* dst){
  __builtin_amdgcn_global_load_lds(
      (const __attribute__((address_space(1))) unsigned int*)src,
      (__attribute__((address_space(3))) unsigned int*)dst, 16, 0, 0);
}

// ---------------- init: zero pad borders + accumulators + csr counters ------
__global__ void k_init(unsigned short* xe_pad, unsigned short* xp1_pad,
                       float* xnode_acc, int* cnt, int* pos){
  int idx = blockIdx.x*256 + threadIdx.x;
  int total_b = NIMG*132*16;
  for(int i = idx; i < total_b; i += gridDim.x*256){
    int img = i / (132*16);
    int rem = i - img*(132*16);
    int bp = rem >> 4;
    int slot = rem & 15;
    int r, c;
    if(bp < 34){ r = 0; c = bp; }
    else if(bp < 68){ r = 33; c = bp-34; }
    else if(bp < 100){ r = bp-68+1; c = 0; }
    else { r = bp-100+1; c = 33; }
    size_t off = ((size_t)img*PPIX + r*PW2 + c)*128 + slot*8;
    uint4 z = {0,0,0,0};
    *(uint4*)(xe_pad + off) = z;
    *(uint4*)(xp1_pad + off) = z;
  }
  for(int i = idx; i < NIMG*HIDC; i += gridDim.x*256) xnode_acc[i] = 0.f;
  for(int i = idx; i < NIMG; i += gridDim.x*256){ cnt[i] = 0; pos[i] = 0; }
}

// ---------------- weight conversion ------------------------------------------
// conv3 W image: [tap][co][slot 0..15][8] bf16; slot holds cin-group (slot-3co)&15.
__global__ void k_wconv(const float* __restrict__ sp_w1, const float* __restrict__ sp_w2,
                        const float* __restrict__ fe_w, const float* __restrict__ op_w,
                        unsigned short* Wb1, unsigned short* Wb2,
                        unsigned short* Wfe, unsigned short* Wop){
  int idx = blockIdx.x*256 + threadIdx.x;
  for(int i = idx; i < 147456; i += gridDim.x*256){
    int j = i & 7, slot = (i>>3)&15, co = (i>>7)&127, tap = i>>14;
    int cin = (((slot - 3*co) & 15)<<3) + j;
    Wb1[i] = f2bf(sp_w1[(co*128+cin)*9 + tap]);
    Wb2[i] = f2bf(sp_w2[(co*128+cin)*9 + tap]);
  }
  for(int i = idx; i < 8192; i += gridDim.x*256){
    int j = i & 7, s = (i>>3)&7, co = i>>6;
    int ci = ((s ^ (co&7))<<3) + j;
    Wfe[i] = f2bf(fe_w[co*64+ci]);
  }
  for(int i = idx; i < 8192; i += gridDim.x*256){
    int j = i & 7, s = (i>>3)&15, co = i>>7;   // co 0..63
    int cin = ((s ^ (co&7))<<3) + j;
    Wop[i] = f2bf(op_w[co*128+cin]);
  }
}

// ---------------- CSR build ------------------------------------------------
__global__ void k_csr_count(const int* __restrict__ ei, int* cnt){
  int e = blockIdx.x*256 + threadIdx.x;
  if(e < NEDGE) atomicAdd(&cnt[ei[NEDGE+e]], 1);
}
__global__ void k_csr_scan(const int* __restrict__ cnt, int* offs){
  __shared__ int sc[512];
  int t = threadIdx.x;
  sc[t] = cnt[t] + 1;   // +1 for self loop
  __syncthreads();
  for(int o = 1; o < 512; o <<= 1){
    int add = (t >= o) ? sc[t-o] : 0;
    __syncthreads();
    sc[t] += add;
    __syncthreads();
  }
  if(t == 0) offs[0] = 0;
  offs[t+1] = sc[t];
}
__global__ void k_csr_fill(const int* __restrict__ ei, const int* __restrict__ offs,
                           int* pos, int* csr_src){
  int e = blockIdx.x*256 + threadIdx.x;
  if(e < NEDGE + NIMG){
    int s, d;
    if(e < NEDGE){ s = ei[e]; d = ei[NEDGE+e]; }
    else { s = e - NEDGE; d = s; }
    int slot = offs[d] + atomicAdd(&pos[d], 1);
    csr_src[slot] = s;
  }
}

// ---------------- encode: 1x1 conv + BN + relu + conf, padded NHWC (baked) --
__launch_bounds__(256, 2)
__global__ void k_encode(const float* __restrict__ x, const float* __restrict__ conf,
                         const unsigned short* __restrict__ Wfe,
                         const float* __restrict__ fe_b, const float* __restrict__ fe_g,
                         const float* __restrict__ fe_beta,
                         unsigned short* __restrict__ xe_pad){
  __shared__ char lds[49152];          // xa 32KB (f32 swizzled) + wb 16KB
  char* xa = lds; char* wb = lds + 32768;
  int tid = threadIdx.x;
  int n = blockIdx.x >> 3, rg = blockIdx.x & 7;
  int hw0 = rg*128;
  {
    int q = tid >> 3, c0 = tid & 7;
    const float* xb = x + (size_t)n*CINCH*HWPIX + hw0;
    #pragma unroll
    for(int cc = 0; cc < 8; ++cc){
      int c = cc*8 + c0;
      float4 v = *(const float4*)(xb + (size_t)c*HWPIX + q*4);
      float vv[4] = {v.x, v.y, v.z, v.w};
      #pragma unroll
      for(int i = 0; i < 4; ++i){
        int p = q*4 + i;
        *(float*)(xa + p*256 + ((cc ^ (p&7))*32) + c0*4) = vv[i];
      }
    }
    #pragma unroll
    for(int it = 0; it < 4; ++it){
      uint4 w = *(const uint4*)((const char*)Wfe + it*4096 + tid*16);
      *(uint4*)(wb + it*4096 + tid*16) = w;
    }
  }
  __syncthreads();
  int wid = tid>>6, lane = tid&63;
  int wr = wid>>1, wc = wid&1, fr = lane&15, fq = lane>>4;
  f32x4 acc[4][4];
  #pragma unroll
  for(int a = 0; a < 4; ++a)
    #pragma unroll
    for(int b = 0; b < 4; ++b) acc[a][b] = (f32x4){0.f,0.f,0.f,0.f};
  #pragma unroll
  for(int kc = 0; kc < 2; ++kc){
    bf16x8 af[4], bfr[4];
    #pragma unroll
    for(int mi = 0; mi < 4; ++mi){
      int p = wr*64 + mi*16 + fr;
      int u = kc*4 + fq;
      const float* src = (const float*)(xa + p*256 + ((u ^ (p&7))*32));
      float4 lo = *(const float4*)src;
      float4 hi = *(const float4*)(src+4);
      bf16x8 a;
      a[0]=(short)f2bf(lo.x); a[1]=(short)f2bf(lo.y); a[2]=(short)f2bf(lo.z); a[3]=(short)f2bf(lo.w);
      a[4]=(short)f2bf(hi.x); a[5]=(short)f2bf(hi.y); a[6]=(short)f2bf(hi.z); a[7]=(short)f2bf(hi.w);
      af[mi] = a;
    }
    #pragma unroll
    for(int nf = 0; nf < 4; ++nf){
      int co = wc*64 + nf*16 + fr;
      int slot = (kc*4 + fq) ^ (co&7);
      bfr[nf] = *(const bf16x8*)(wb + co*128 + slot*16);
    }
    #pragma unroll
    for(int mi = 0; mi < 4; ++mi)
      #pragma unroll
      for(int nf = 0; nf < 4; ++nf)
        acc[mi][nf] = __builtin_amdgcn_mfma_f32_16x16x32_bf16(af[mi], bfr[nf], acc[mi][nf], 0,0,0);
  }
  __syncthreads();
  {
    const float rs = 0.9999950000374997f;
    float kb[4], ks[4], kbe[4];
    #pragma unroll
    for(int nf = 0; nf < 4; ++nf){
      int co = wc*64 + nf*16 + fr;
      kb[nf] = fe_b[co]; ks[nf] = fe_g[co]*rs; kbe[nf] = fe_beta[co];
    }
    #pragma unroll
    for(int mi = 0; mi < 4; ++mi)
      #pragma unroll
      for(int j = 0; j < 4; ++j){
        int px = wr*64 + mi*16 + fq*4 + j;
        float cf = conf[(size_t)n*HWPIX + hw0 + px];
        #pragma unroll
        for(int nf = 0; nf < 4; ++nf){
          float v = (acc[mi][nf][j] + kb[nf])*ks[nf] + kbe[nf];
          v = fmaxf(v, 0.f)*cf;
          int co = wc*64 + nf*16 + fr;
          *(unsigned short*)(xa + px*256 + ((co*2) ^ (((px>>2)&7)<<4))) = f2bf(v);
        }
      }
  }
  __syncthreads();
  {
    int p = tid>>1, half = tid&1;
    int r = rg*4 + (p>>5), c = p&31;
    int key = 2*((p&31) + 1);                // additive key, padded col
    unsigned short* dst = xe_pad + ((size_t)n*PPIX + (r+1)*PW2 + (c+1))*128;
    #pragma unroll
    for(int s = 0; s < 8; ++s){
      int ls = half*8 + s;
      uint4 v = *(uint4*)(xa + p*256 + ((ls*16) ^ (((p>>2)&7)<<4)));
      *(uint4*)(dst + ((ls + key)&15)*8) = v;
    }
  }
}

// ---------------- 3x3 conv: 8 waves, 64px x 64co wave tile, 32x32x16 MFMA ---
// R9 geometry + schedule changes: (1) 2-deep register pipelining of kc
// operands (load kc+1 before kc's MFMA cluster -> LDS latency hidden under
// MFMA, continuous LDS issue); (2) per-wave kc rotation (kc_i=(i+wid)&7,
// accumulation commutes) to decorrelate the 8 waves' LDS access timing.
__launch_bounds__(512, 2)
__global__ void k_conv3(const unsigned short* __restrict__ inp,   // padded, baked
                        const unsigned short* __restrict__ Wb,    // [9][128][16][8] baked
                        const float* __restrict__ bnb, const float* __restrict__ bng,
                        const float* __restrict__ bnbe,
                        unsigned short* __restrict__ outp,
                        float* __restrict__ xnode_acc, int mode){
  extern __shared__ char lds[];
  char* Ab = lds;                 // 93184 (5824 granules; >=5780 used)
  char* Wd = lds + 93184;         // 2 x 32768
  int tid = threadIdx.x;
  int n = blockIdx.x>>2, rg = blockIdx.x&3;

  const char* img  = (const char*)inp + ((size_t)n*PPIX + (size_t)rg*8*PW2)*256;
  const char* wsrc = (const char*)Wb;

  // prologue: stage W tap0 + A tile (272-pitch LDS, 256-pitch global)
  #pragma unroll
  for(int it = 0; it < 4; ++it)
    gload16(wsrc + it*8192 + tid*16, Wd + it*8192 + tid*16);
  #pragma unroll
  for(int it = 0; it < 12; ++it){
    int j = tid + it*512;
    if(it < 11 || j < 5824){          // tail = 192 threads = 3 FULL waves
      int pidx = j/17, s = j - pidx*17;
      if(pidx > 339) pidx = 339;      // clamp: dead region, never read
      if(s == 16) s = 0;              // dead slot: dup-load keeps lane active
      gload16(img + (size_t)pidx*256 + s*16, Ab + (size_t)j*16);
    }
  }

  int wid = tid>>6, lane = tid&63;
  int wr = wid>>1, wc = wid&1;                 // wr 0..3 (row pair), wc 0..1
  int col = lane&31, hi = lane>>5;
  int cob = (wc*64 + col)*256;                 // nf=0 W row base

  f32x16 acc[2][2];
  #pragma unroll
  for(int a = 0; a < 2; ++a)
    #pragma unroll
    for(int b = 0; b < 2; ++b)
      #pragma unroll
      for(int r = 0; r < 16; ++r) acc[a][b][r] = 0.f;

  __syncthreads();

  for(int tap = 0; tap < 9; ++tap){
    if(tap < 8){
      const char* ws = wsrc + (size_t)(tap+1)*32768;
      char* wdst = Wd + ((tap+1)&1)*32768;
      #pragma unroll
      for(int it = 0; it < 4; ++it)
        gload16(ws + it*8192 + tid*16, wdst + it*8192 + tid*16);
    }
    const char* cur = Wd + (tap&1)*32768;
    int dy = tap/3 - 1, dx = tap - (tap/3)*3 - 1;
    int pcol = col + 1 + dx;
    int prow0 = wr*2 + 1 + dy;                  // 0..9
    int a0b = prow0*AROW + pcol*APITCH;
    int ka = 2*pcol;                            // additive A slot key

    // 2-deep register-pipelined kc loop, per-wave rotated start
    int kc0 = wid & 7;
    int g0 = kc0*2 + hi;
    int sa0 = ((g0 + ka)&15)<<4;
    int sw0 = ((g0 + 3*col)&15)<<4;
    bf16x8 a0c = *(const bf16x8*)(Ab + a0b + sa0);
    bf16x8 a1c = *(const bf16x8*)(Ab + a0b + AROW + sa0);
    bf16x8 w0c = *(const bf16x8*)(cur + cob + sw0);
    bf16x8 w1c = *(const bf16x8*)(cur + cob + 8192 + sw0);
    __builtin_amdgcn_s_setprio(1);
    #pragma unroll
    for(int i = 0; i < 8; ++i){
      bf16x8 a0n, a1n, w0n, w1n;
      if(i < 7){
        int kcn = (wid + i + 1) & 7;
        int gn = kcn*2 + hi;
        int san = ((gn + ka)&15)<<4;
        int swn = ((gn + 3*col)&15)<<4;
        a0n = *(const bf16x8*)(Ab + a0b + san);
        a1n = *(const bf16x8*)(Ab + a0b + AROW + san);
        w0n = *(const bf16x8*)(cur + cob + swn);
        w1n = *(const bf16x8*)(cur + cob + 8192 + swn);
      }
      acc[0][0] = __builtin_amdgcn_mfma_f32_32x32x16_bf16(a0c, w0c, acc[0][0], 0,0,0);
      acc[0][1] = __builtin_amdgcn_mfma_f32_32x32x16_bf16(a0c, w1c, acc[0][1], 0,0,0);
      acc[1][0] = __builtin_amdgcn_mfma_f32_32x32x16_bf16(a1c, w0c, acc[1][0], 0,0,0);
      acc[1][1] = __builtin_amdgcn_mfma_f32_32x32x16_bf16(a1c, w1c, acc[1][1], 0,0,0);
      if(i < 7){ a0c = a0n; a1c = a1n; w0c = w0n; w1c = w1n; }
    }
    __builtin_amdgcn_s_setprio(0);
    __syncthreads();   // all reads of cur done + next stage landed (vmcnt drain)
  }

  // epilogue: BN + relu -> LDS transpose scratch (reuse A region), xnode regs
  char* eb = Ab;
  float sn0 = 0.f, sn1 = 0.f;
  {
    const float rs = 0.9999950000374997f;
    float kb[2], ks[2], kbe[2];
    #pragma unroll
    for(int nf = 0; nf < 2; ++nf){
      int co = wc*64 + nf*32 + col;
      kb[nf] = bnb[co]; ks[nf] = bng[co]*rs; kbe[nf] = bnbe[co];
    }
    #pragma unroll
    for(int mi = 0; mi < 2; ++mi)
      #pragma unroll
      for(int reg = 0; reg < 16; ++reg){
        int pc = (reg&3) + 8*(reg>>2) + 4*hi;
        int px = (wr*2 + mi)*32 + pc;           // block-local 0..255
        #pragma unroll
        for(int nf = 0; nf < 2; ++nf){
          float v = (acc[mi][nf][reg] + kb[nf])*ks[nf] + kbe[nf];
          v = fmaxf(v, 0.f);
          if(nf == 0) sn0 += v; else sn1 += v;
          int co = wc*64 + nf*32 + col;
          *(unsigned short*)(eb + px*256 + ((co*2) ^ (((px>>2)&7)<<4))) = f2bf(v);
        }
      }
  }
  if(mode == 1){
    sn0 += __shfl_down(sn0, 32);
    sn1 += __shfl_down(sn1, 32);
    if(lane < 32){
      atomicAdd(&xnode_acc[n*HIDC + wc*64 + col], sn0);
      atomicAdd(&xnode_acc[n*HIDC + wc*64 + 32 + col], sn1);
    }
  }
  __syncthreads();
  {
    int p = tid>>1, half = tid&1;               // p 0..255
    int r = rg*8 + (p>>5), c = p&31;
    unsigned short* dst;
    int key;
    if(mode == 0){
      key = 2*((p&31) + 1);                     // padded additive key
      dst = outp + ((size_t)n*PPIX + (r+1)*PW2 + (c+1))*128;
    } else {
      key = 3*p;                                 // flat additive key (3*hw mod 16)
      dst = outp + ((size_t)n*HWPIX + rg*256 + p)*128;
    }
    #pragma unroll
    for(int s = 0; s < 8; ++s){
      int ls = half*8 + s;
      uint4 v = *(uint4*)(eb + p*256 + ((ls*16) ^ (((p>>2)&7)<<4)));
      *(uint4*)(dst + ((ls + key)&15)*8) = v;
    }
  }
}

// ---------------- GAT linear: h = x@lin, plus per-head attn dots ------------
__global__ void k_gat_lin(const float* __restrict__ xin, float scale,
                          const float* __restrict__ lin,
                          const float* __restrict__ as_, const float* __restrict__ ad_,
                          float* __restrict__ h, float* __restrict__ a_s, float* __restrict__ a_d){
  __shared__ float xs[128];
  __shared__ float rs0[4], rs1[4], rd0[4], rd1[4];
  int n = blockIdx.x, t = threadIdx.x;
  if(t < 128) xs[t] = xin[n*128 + t]*scale;
  __syncthreads();
  float o0 = 0.f, o1 = 0.f;
  for(int k = 0; k < 128; ++k){
    float xv = xs[k];
    o0 += xv*lin[k*512 + t];
    o1 += xv*lin[k*512 + t + 256];
  }
  h[(size_t)n*512 + t] = o0;
  h[(size_t)n*512 + t + 256] = o1;
  float s0 = o0*as_[t], s1 = o1*as_[t+256];
  float d0 = o0*ad_[t], d1 = o1*ad_[t+256];
  #pragma unroll
  for(int o = 32; o; o >>= 1){
    s0 += __shfl_down(s0, o); s1 += __shfl_down(s1, o);
    d0 += __shfl_down(d0, o); d1 += __shfl_down(d1, o);
  }
  int w = t>>6;
  if((t&63) == 0){ rs0[w]=s0; rs1[w]=s1; rd0[w]=d0; rd1[w]=d1; }
  __syncthreads();
  if(t < 4){
    if(t < 2){
      a_s[n*4+t] = rs0[2*t] + rs0[2*t+1];
      a_d[n*4+t] = rd0[2*t] + rd0[2*t+1];
    } else {
      a_s[n*4+t] = rs1[2*(t-2)] + rs1[2*(t-2)+1];
      a_d[n*4+t] = rd1[2*(t-2)] + rd1[2*(t-2)+1];
    }
  }
}

// ---------------- GAT aggregate: per-dst softmax + weighted sum -------------
__global__ void k_gat_aggr(const int* __restrict__ offs, const int* __restrict__ csr_src,
                           const float* __restrict__ a_s, const float* __restrict__ a_d,
                           const float* __restrict__ h, const float* __restrict__ bias,
                           float* __restrict__ y){
  __shared__ int ssrc[2048];
  __shared__ float sex[4][2048];
  __shared__ float out4[512];
  __shared__ float adn[4], smax[4], sden[4];
  __shared__ float wred[4][4];
  int n = blockIdx.x, t = threadIdx.x;
  int base = offs[n], deg = offs[n+1] - base;
  if(t < 4) adn[t] = a_d[n*4 + t];
  __syncthreads();
  bool cached = (deg <= 2048);
  float lm0=-1e30f, lm1=-1e30f, lm2=-1e30f, lm3=-1e30f;
  for(int e = t; e < deg; e += 256){
    int s = csr_src[base + e];
    float v0 = a_s[s*4+0] + adn[0]; v0 = v0 > 0.f ? v0 : 0.2f*v0;
    float v1 = a_s[s*4+1] + adn[1]; v1 = v1 > 0.f ? v1 : 0.2f*v1;
    float v2 = a_s[s*4+2] + adn[2]; v2 = v2 > 0.f ? v2 : 0.2f*v2;
    float v3 = a_s[s*4+3] + adn[3]; v3 = v3 > 0.f ? v3 : 0.2f*v3;
    if(cached){ ssrc[e]=s; sex[0][e]=v0; sex[1][e]=v1; sex[2][e]=v2; sex[3][e]=v3; }
    lm0 = fmaxf(lm0, v0); lm1 = fmaxf(lm1, v1); lm2 = fmaxf(lm2, v2); lm3 = fmaxf(lm3, v3);
  }
  #pragma unroll
  for(int o = 32; o; o >>= 1){
    lm0 = fmaxf(lm0, __shfl_down(lm0, o)); lm1 = fmaxf(lm1, __shfl_down(lm1, o));
    lm2 = fmaxf(lm2, __shfl_down(lm2, o)); lm3 = fmaxf(lm3, __shfl_down(lm3, o));
  }
  int w = t>>6;
  if((t&63) == 0){ wred[w][0]=lm0; wred[w][1]=lm1; wred[w][2]=lm2; wred[w][3]=lm3; }
  __syncthreads();
  if(t < 4) smax[t] = fmaxf(fmaxf(wred[0][t], wred[1][t]), fmaxf(wred[2][t], wred[3][t]));
  __syncthreads();
  float m0 = smax[0], m1 = smax[1], m2 = smax[2], m3 = smax[3];
  float ls0=0.f, ls1=0.f, ls2=0.f, ls3=0.f;
  for(int e = t; e < deg; e += 256){
    float e0, e1, e2, e3;
    if(cached){ e0 = sex[0][e]; e1 = sex[1][e]; e2 = sex[2][e]; e3 = sex[3][e]; }
    else {
      int s = csr_src[base + e];
      e0 = a_s[s*4+0] + adn[0]; e0 = e0 > 0.f ? e0 : 0.2f*e0;
      e1 = a_s[s*4+1] + adn[1]; e1 = e1 > 0.f ? e1 : 0.2f*e1;
      e2 = a_s[s*4+2] + adn[2]; e2 = e2 > 0.f ? e2 : 0.2f*e2;
      e3 = a_s[s*4+3] + adn[3]; e3 = e3 > 0.f ? e3 : 0.2f*e3;
    }
    e0 = __expf(e0-m0); e1 = __expf(e1-m1); e2 = __expf(e2-m2); e3 = __expf(e3-m3);
    if(cached){ sex[0][e]=e0; sex[1][e]=e1; sex[2][e]=e2; sex[3][e]=e3; }
    ls0 += e0; ls1 += e1; ls2 += e2; ls3 += e3;
  }
  #pragma unroll
  for(int o = 32; o; o >>= 1){
    ls0 += __shfl_down(ls0, o); ls1 += __shfl_down(ls1, o);
    ls2 += __shfl_down(ls2, o); ls3 += __shfl_down(ls3, o);
  }
  __syncthreads();   // wred(max) fully consumed
  if((t&63) == 0){ wred[w][0]=ls0; wred[w][1]=ls1; wred[w][2]=ls2; wred[w][3]=ls3; }
  __syncthreads();
  if(t < 4) sden[t] = wred[0][t] + wred[1][t] + wred[2][t] + wred[3][t] + 1e-16f;
  __syncthreads();
  #pragma unroll
  for(int oo = 0; oo < 2; ++oo){
    int o = t + oo*256;
    int hd = o>>7, d = o&127;
    float mh = smax[hd];
    float accv = 0.f;
    for(int e = 0; e < deg; ++e){
      float ex; int s;
      if(cached){ ex = sex[hd][e]; s = ssrc[e]; }
      else {
        s = csr_src[base + e];
        float v = a_s[s*4+hd] + adn[hd]; v = v > 0.f ? v : 0.2f*v;
        ex = __expf(v - mh);
      }
      accv += ex * h[(size_t)s*512 + hd*128 + d];
    }
    out4[o] = accv / sden[hd];
  }
  __syncthreads();
  if(t < 128){
    float v = (out4[t] + out4[128+t] + out4[256+t] + out4[384+t])*0.25f + bias[t];
    y[n*128 + t] = fmaxf(v, 0.f);
  }
}

// ---------------- per-node bias for final conv: nb = op_w @ xg2 + op_b ------
__global__ void k_nodebias(const float* __restrict__ xg2, const float* __restrict__ op_w,
                           const float* __restrict__ op_b, float* __restrict__ nb){
  int g = blockIdx.x*256 + threadIdx.x;
  if(g < NIMG*64){
    int n = g>>6, co = g&63;
    float acc = op_b[co];
    for(int k = 0; k < 128; ++k) acc += op_w[co*128+k]*xg2[n*128+k];
    nb[g] = acc;
  }
}

// ---------------- final 1x1 conv: out = op_w@xp2 + nb, NCHW f32 -------------
__launch_bounds__(256, 2)
__global__ void k_outconv(const unsigned short* __restrict__ xp2,  // flat, slot=(g+3hw)&15
                          const unsigned short* __restrict__ Wop,
                          const float* __restrict__ nb, float* __restrict__ out){
  __shared__ char lds[16384];
  int tid = threadIdx.x;
  int n = blockIdx.x>>3, rg = blockIdx.x&7;
  #pragma unroll
  for(int it = 0; it < 4; ++it){
    uint4 v = *(const uint4*)((const char*)Wop + it*4096 + tid*16);
    *(uint4*)(lds + it*4096 + tid*16) = v;
  }
  __syncthreads();
  int wid = tid>>6, lane = tid&63;
  int wr = wid>>1, wc = wid&1, fr = lane&15, fq = lane>>4;
  f32x4 acc[4][2];
  #pragma unroll
  for(int a = 0; a < 4; ++a){ acc[a][0] = (f32x4){0.f,0.f,0.f,0.f}; acc[a][1] = (f32x4){0.f,0.f,0.f,0.f}; }
  const unsigned short* abase = xp2 + ((size_t)n*HWPIX + rg*128)*128;
  #pragma unroll
  for(int kc = 0; kc < 4; ++kc){
    bf16x8 af[4], bfr[2];
    #pragma unroll
    for(int mi = 0; mi < 4; ++mi){
      int p = wr*64 + mi*16 + fr;
      af[mi] = *(const bf16x8*)(abase + p*128 + (((kc*4+fq) + 3*p)&15)*8);
    }
    #pragma unroll
    for(int nf = 0; nf < 2; ++nf){
      int co = wc*32 + nf*16 + fr;
      int slot = (kc*4 + fq) ^ (co&7);
      bfr[nf] = *(const bf16x8*)(lds + co*256 + slot*16);
    }
    #pragma unroll
    for(int mi = 0; mi < 4; ++mi)
      #pragma unroll
      for(int nf = 0; nf < 2; ++nf)
        acc[mi][nf] = __builtin_amdgcn_mfma_f32_16x16x32_bf16(af[mi], bfr[nf], acc[mi][nf], 0,0,0);
  }
  #pragma unroll
  for(int mi = 0; mi < 4; ++mi)
    #pragma unroll
    for(int nf = 0; nf < 2; ++nf){
      int co = wc*32 + nf*16 + fr;
      int hw = rg*128 + wr*64 + mi*16 + fq*4;
      float nbv = nb[n*64 + co];
      float4 v = { acc[mi][nf][0]+nbv, acc[mi][nf][1]+nbv, acc[mi][nf][2]+nbv, acc[mi][nf][3]+nbv };
      *(float4*)(out + ((size_t)n*64 + co)*HWPIX + hw) = v;
    }
}

// ---------------- host launch ----------------------------------------------
extern "C" void kernel_launch(void* const* d_in, const int* in_sizes, int n_in,
                              void* d_out, int out_size, void* d_ws, size_t ws_size,
                              hipStream_t stream){
  const float* x       = (const float*)d_in[0];
  const int*   ei      = (const int*)d_in[1];
  const float* conf    = (const float*)d_in[2];
  const float* fe_w    = (const float*)d_in[3];
  const float* fe_b    = (const float*)d_in[4];
  const float* fe_g    = (const float*)d_in[5];
  const float* fe_beta = (const float*)d_in[6];
  const float* sp_w1   = (const float*)d_in[7];
  const float* sp_b1   = (const float*)d_in[8];
  const float* sp_g1   = (const float*)d_in[9];
  const float* sp_be1  = (const float*)d_in[10];
  const float* sp_w2   = (const float*)d_in[11];
  const float* sp_b2   = (const float*)d_in[12];
  const float* sp_g2   = (const float*)d_in[13];
  const float* sp_be2  = (const float*)d_in[14];
  const float* g1_lin  = (const float*)d_in[15];
  const float* g1_as   = (const float*)d_in[16];
  const float* g1_ad   = (const float*)d_in[17];
  const float* g1_b    = (const float*)d_in[18];
  const float* g2_lin  = (const float*)d_in[19];
  const float* g2_as   = (const float*)d_in[20];
  const float* g2_ad   = (const float*)d_in[21];
  const float* g2_b    = (const float*)d_in[22];
  const float* op_w    = (const float*)d_in[23];
  const float* op_b    = (const float*)d_in[24];
  float* out = (float*)d_out;

  char* ws = (char*)d_ws;
  size_t off = 0;
  auto alloc = [&](size_t bytes)->char*{
    char* p = ws + off; off += (bytes + 255) & ~(size_t)255; return p;
  };
  unsigned short* bigA  = (unsigned short*)alloc((size_t)NIMG*PPIX*128*2); // xe_pad, later xp2
  unsigned short* xp1   = (unsigned short*)alloc((size_t)NIMG*PPIX*128*2);
  unsigned short* Wb1   = (unsigned short*)alloc(147456*2);
  unsigned short* Wb2   = (unsigned short*)alloc(147456*2);
  unsigned short* Wfe   = (unsigned short*)alloc(8192*2);
  unsigned short* Wop   = (unsigned short*)alloc(8192*2);
  float* xnode_acc = (float*)alloc(NIMG*HIDC*4);
  float* h     = (float*)alloc((size_t)NIMG*512*4);
  float* a_s   = (float*)alloc(NIMG*4*4);
  float* a_d   = (float*)alloc(NIMG*4*4);
  float* xg1   = (float*)alloc(NIMG*HIDC*4);
  float* xg2   = (float*)alloc(NIMG*HIDC*4);
  int* cnt     = (int*)alloc(NIMG*4);
  int* pos     = (int*)alloc(NIMG*4);
  int* offs    = (int*)alloc((NIMG+1)*4);
  int* csr_src = (int*)alloc((NEDGE+NIMG)*4);
  float* nb    = (float*)alloc(NIMG*64*4);
  if(off > ws_size) return;   // workspace too small — bail cleanly
  unsigned short* xp2 = bigA; // reuse region A after conv1 consumed xe

  // 158720 B dynamic LDS for k_conv3 (A 93184 + W dbuf 65536); 1 block/CU.
  hipFuncSetAttribute((const void*)k_conv3,
                      hipFuncAttributeMaxDynamicSharedMemorySize, 158720);

  k_init<<<1024, 256, 0, stream>>>(bigA, xp1, xnode_acc, cnt, pos);
  k_wconv<<<576, 256, 0, stream>>>(sp_w1, sp_w2, fe_w, op_w, Wb1, Wb2, Wfe, Wop);
  k_csr_count<<<(NEDGE+255)/256, 256, 0, stream>>>(ei, cnt);
  k_csr_scan<<<1, 512, 0, stream>>>(cnt, offs);
  k_csr_fill<<<(NEDGE+NIMG+255)/256, 256, 0, stream>>>(ei, offs, pos, csr_src);
  k_encode<<<4096, 256, 0, stream>>>(x, conf, Wfe, fe_b, fe_g, fe_beta, bigA);
  k_conv3<<<2048, 512, 158720, stream>>>(bigA, Wb1, sp_b1, sp_g1, sp_be1, xp1, xnode_acc, 0);
  k_conv3<<<2048, 512, 158720, stream>>>(xp1, Wb2, sp_b2, sp_g2, sp_be2, xp2, xnode_acc, 1);
  k_gat_lin<<<512, 256, 0, stream>>>(xnode_acc, 1.f/1024.f, g1_lin, g1_as, g1_ad, h, a_s, a_d);
  k_gat_aggr<<<512, 256, 0, stream>>>(offs, csr_src, a_s, a_d, h, g1_b, xg1);
  k_gat_lin<<<512, 256, 0, stream>>>(xg1, 1.f, g2_lin, g2_as, g2_ad, h, a_s, a_d);
  k_gat_aggr<<<512, 256, 0, stream>>>(offs, csr_src, a_s, a_d, h, g2_b, xg2);
  k_nodebias<<<(NIMG*64+255)/256, 256, 0, stream>>>(xg2, op_w, op_b, nb);
  k_outconv<<<4096, 256, 0, stream>>>(xp2, Wop, nb, out);
}

// Round 13
// 554.355 us; speedup vs baseline: 1.1267x; 1.0911x over previous
//
#include <hip/hip_runtime.h>
#include <stdint.h>

#define NIMG 512
#define CINCH 64
#define HIDC 128
#define NEDGE 16384
#define HWPIX 1024
#define PW2 34
#define PPIX 1156   // 34*34
#define APITCH 144  // LDS A-tile pixel pitch (8 granules + 1 dead)
#define AROW 4896   // 34*144

typedef __attribute__((ext_vector_type(8))) short bf16x8;
typedef __attribute__((ext_vector_type(4))) float f32x4;
typedef __attribute__((ext_vector_type(16))) float f32x16;

static __device__ __forceinline__ unsigned short f2bf(float f){
  unsigned u = __builtin_bit_cast(unsigned, f);
  u += 0x7FFFu + ((u>>16)&1u);
  return (unsigned short)(u>>16);
}
static __device__ __forceinline__ float bf2f(unsigned short s){
  unsigned u = ((unsigned)s)<<16;
  return __builtin_bit_cast(float, u);
}

// async 16B global->LDS, LDS side linear per wave (m104)
static __device__ __forceinline__ void gload16(const char* src, char* dst){
  __builtin_amdgcn_global_load_lds(
      (const __attribute__((address_space(1))) unsigned int*)src,
      (__attribute__((address_space(3))) unsigned int*)dst, 16, 0, 0);
}

// ---------------- init: zero pad borders + accumulators + csr counters ------
__global__ void k_init(unsigned short* xe_pad, unsigned short* xp1_pad,
                       float* xnode_acc, int* cnt, int* pos){
  int idx = blockIdx.x*256 + threadIdx.x;
  int total_b = NIMG*132*16;
  for(int i = idx; i < total_b; i += gridDim.x*256){
    int img = i / (132*16);
    int rem = i - img*(132*16);
    int bp = rem >> 4;
    int slot = rem & 15;
    int r, c;
    if(bp < 34){ r = 0; c = bp; }
    else if(bp < 68){ r = 33; c = bp-34; }
    else if(bp < 100){ r = bp-68+1; c = 0; }
    else { r = bp-100+1; c = 33; }
    size_t off = ((size_t)img*PPIX + r*PW2 + c)*128 + slot*8;
    uint4 z = {0,0,0,0};
    *(uint4*)(xe_pad + off) = z;
    *(uint4*)(xp1_pad + off) = z;
  }
  for(int i = idx; i < NIMG*HIDC; i += gridDim.x*256) xnode_acc[i] = 0.f;
  for(int i = idx; i < NIMG; i += gridDim.x*256){ cnt[i] = 0; pos[i] = 0; }
}

// ---------------- weight conversion ------------------------------------------
// conv3 W: 18 images of 16KB in STAGE ORDER img = h*9 + tap (matches q loop).
// Image layout [co][pos 0..7][8]; pos holds cin-group (pos-3co)&7 within half h.
__global__ void k_wconv(const float* __restrict__ sp_w1, const float* __restrict__ sp_w2,
                        const float* __restrict__ fe_w, const float* __restrict__ op_w,
                        unsigned short* Wb1, unsigned short* Wb2,
                        unsigned short* Wfe, unsigned short* Wop){
  int idx = blockIdx.x*256 + threadIdx.x;
  for(int i = idx; i < 147456; i += gridDim.x*256){
    int j = i & 7, pos = (i>>3)&7, co = (i>>6)&127, img = i>>13;  // img 0..17
    int h = img/9, tap = img - 9*h;
    int cin = h*64 + (((pos - 3*co) & 7)<<3) + j;
    Wb1[i] = f2bf(sp_w1[(co*128+cin)*9 + tap]);
    Wb2[i] = f2bf(sp_w2[(co*128+cin)*9 + tap]);
  }
  for(int i = idx; i < 8192; i += gridDim.x*256){
    int j = i & 7, s = (i>>3)&7, co = i>>6;
    int ci = ((s ^ (co&7))<<3) + j;
    Wfe[i] = f2bf(fe_w[co*64+ci]);
  }
  for(int i = idx; i < 8192; i += gridDim.x*256){
    int j = i & 7, s = (i>>3)&15, co = i>>7;   // co 0..63
    int cin = ((s ^ (co&7))<<3) + j;
    Wop[i] = f2bf(op_w[co*128+cin]);
  }
}

// ---------------- CSR build ------------------------------------------------
__global__ void k_csr_count(const int* __restrict__ ei, int* cnt){
  int e = blockIdx.x*256 + threadIdx.x;
  if(e < NEDGE) atomicAdd(&cnt[ei[NEDGE+e]], 1);
}
__global__ void k_csr_scan(const int* __restrict__ cnt, int* offs){
  __shared__ int sc[512];
  int t = threadIdx.x;
  sc[t] = cnt[t] + 1;   // +1 for self loop
  __syncthreads();
  for(int o = 1; o < 512; o <<= 1){
    int add = (t >= o) ? sc[t-o] : 0;
    __syncthreads();
    sc[t] += add;
    __syncthreads();
  }
  if(t == 0) offs[0] = 0;
  offs[t+1] = sc[t];
}
__global__ void k_csr_fill(const int* __restrict__ ei, const int* __restrict__ offs,
                           int* pos, int* csr_src){
  int e = blockIdx.x*256 + threadIdx.x;
  if(e < NEDGE + NIMG){
    int s, d;
    if(e < NEDGE){ s = ei[e]; d = ei[NEDGE+e]; }
    else { s = e - NEDGE; d = s; }
    int slot = offs[d] + atomicAdd(&pos[d], 1);
    csr_src[slot] = s;
  }
}

// ---------------- encode: 1x1 conv + BN + relu + conf, padded NHWC (baked) --
__launch_bounds__(256, 2)
__global__ void k_encode(const float* __restrict__ x, const float* __restrict__ conf,
                         const unsigned short* __restrict__ Wfe,
                         const float* __restrict__ fe_b, const float* __restrict__ fe_g,
                         const float* __restrict__ fe_beta,
                         unsigned short* __restrict__ xe_pad){
  __shared__ char lds[49152];          // xa 32KB (f32 swizzled) + wb 16KB
  char* xa = lds; char* wb = lds + 32768;
  int tid = threadIdx.x;
  int n = blockIdx.x >> 3, rg = blockIdx.x & 7;
  int hw0 = rg*128;
  {
    int q = tid >> 3, c0 = tid & 7;
    const float* xb = x + (size_t)n*CINCH*HWPIX + hw0;
    #pragma unroll
    for(int cc = 0; cc < 8; ++cc){
      int c = cc*8 + c0;
      float4 v = *(const float4*)(xb + (size_t)c*HWPIX + q*4);
      float vv[4] = {v.x, v.y, v.z, v.w};
      #pragma unroll
      for(int i = 0; i < 4; ++i){
        int p = q*4 + i;
        *(float*)(xa + p*256 + ((cc ^ (p&7))*32) + c0*4) = vv[i];
      }
    }
    #pragma unroll
    for(int it = 0; it < 4; ++it){
      uint4 w = *(const uint4*)((const char*)Wfe + it*4096 + tid*16);
      *(uint4*)(wb + it*4096 + tid*16) = w;
    }
  }
  __syncthreads();
  int wid = tid>>6, lane = tid&63;
  int wr = wid>>1, wc = wid&1, fr = lane&15, fq = lane>>4;
  f32x4 acc[4][4];
  #pragma unroll
  for(int a = 0; a < 4; ++a)
    #pragma unroll
    for(int b = 0; b < 4; ++b) acc[a][b] = (f32x4){0.f,0.f,0.f,0.f};
  #pragma unroll
  for(int kc = 0; kc < 2; ++kc){
    bf16x8 af[4], bfr[4];
    #pragma unroll
    for(int mi = 0; mi < 4; ++mi){
      int p = wr*64 + mi*16 + fr;
      int u = kc*4 + fq;
      const float* src = (const float*)(xa + p*256 + ((u ^ (p&7))*32));
      float4 lo = *(const float4*)src;
      float4 hi = *(const float4*)(src+4);
      bf16x8 a;
      a[0]=(short)f2bf(lo.x); a[1]=(short)f2bf(lo.y); a[2]=(short)f2bf(lo.z); a[3]=(short)f2bf(lo.w);
      a[4]=(short)f2bf(hi.x); a[5]=(short)f2bf(hi.y); a[6]=(short)f2bf(hi.z); a[7]=(short)f2bf(hi.w);
      af[mi] = a;
    }
    #pragma unroll
    for(int nf = 0; nf < 4; ++nf){
      int co = wc*64 + nf*16 + fr;
      int slot = (kc*4 + fq) ^ (co&7);
      bfr[nf] = *(const bf16x8*)(wb + co*128 + slot*16);
    }
    #pragma unroll
    for(int mi = 0; mi < 4; ++mi)
      #pragma unroll
      for(int nf = 0; nf < 4; ++nf)
        acc[mi][nf] = __builtin_amdgcn_mfma_f32_16x16x32_bf16(af[mi], bfr[nf], acc[mi][nf], 0,0,0);
  }
  __syncthreads();
  {
    const float rs = 0.9999950000374997f;
    float kb[4], ks[4], kbe[4];
    #pragma unroll
    for(int nf = 0; nf < 4; ++nf){
      int co = wc*64 + nf*16 + fr;
      kb[nf] = fe_b[co]; ks[nf] = fe_g[co]*rs; kbe[nf] = fe_beta[co];
    }
    #pragma unroll
    for(int mi = 0; mi < 4; ++mi)
      #pragma unroll
      for(int j = 0; j < 4; ++j){
        int px = wr*64 + mi*16 + fq*4 + j;
        float cf = conf[(size_t)n*HWPIX + hw0 + px];
        #pragma unroll
        for(int nf = 0; nf < 4; ++nf){
          float v = (acc[mi][nf][j] + kb[nf])*ks[nf] + kbe[nf];
          v = fmaxf(v, 0.f)*cf;
          int co = wc*64 + nf*16 + fr;
          *(unsigned short*)(xa + px*256 + ((co*2) ^ (((px>>2)&7)<<4))) = f2bf(v);
        }
      }
  }
  __syncthreads();
  {
    int p = tid>>1, half = tid&1;
    int r = rg*4 + (p>>5), c = p&31;
    int key = 2*((p&31) + 1);                // additive key, padded col (mod 8)
    unsigned short* dst = xe_pad + ((size_t)n*PPIX + (r+1)*PW2 + (c+1))*128;
    #pragma unroll
    for(int s = 0; s < 8; ++s){
      int ls = half*8 + s;                   // semantic granule 0..15
      uint4 v = *(uint4*)(xa + p*256 + ((ls*16) ^ (((p>>2)&7)<<4)));
      int pos = (ls>>3)*8 + (((ls&7) + key)&7);
      *(uint4*)(dst + pos*8) = v;
    }
  }
}

// ---------------- 3x3 conv: K-split, 256 thr / 4 waves, 2 blocks/CU ---------
// Block tile 8 rows x 128 co; K in two 64-ch halves (A half-tile re-staged at
// h switch). Wave tile 128px x 64co, acc f32x16[4][2]. LDS = A 340px x 144B
// (+192B gap) + W dbuf 2x16KB = 81920B exactly -> 2 independent barrier
// groups per CU overlap LDS-read phases with MFMA phases.
__launch_bounds__(256, 2)
__global__ void k_conv3(const unsigned short* __restrict__ inp,   // padded, baked
                        const unsigned short* __restrict__ Wb,    // [h*9+tap][128][8][8]
                        const float* __restrict__ bnb, const float* __restrict__ bng,
                        const float* __restrict__ bnbe,
                        unsigned short* __restrict__ outp,
                        float* __restrict__ xnode_acc, int mode){
  extern __shared__ char lds[];
  char* Ab = lds;                 // 48960 used + 192 gap (clamped dup-loads)
  char* Wd = lds + 49152;         // 2 x 16384
  int tid = threadIdx.x;
  int n = blockIdx.x>>2, rg = blockIdx.x&3;

  const char* img  = (const char*)inp + ((size_t)n*PPIX + (size_t)rg*8*PW2)*256;
  const char* wsrc = (const char*)Wb;

  // prologue: W(q=0) + A(h=0); all lanes of all waves active, linear LDS dst
  #pragma unroll
  for(int it = 0; it < 4; ++it)
    gload16(wsrc + it*4096 + tid*16, Wd + it*4096 + tid*16);
  #pragma unroll
  for(int it = 0; it < 12; ++it){
    int j = tid + it*256;             // 0..3071 (3060 real, rest clamped dup)
    int q9 = j/9;
    int s = j - 9*q9;                  // 0..8
    int pidx = q9 > 339 ? 339 : q9;
    int ss = (s == 8) ? 0 : s;
    gload16(img + (size_t)pidx*256 + 0*128 + ss*16, Ab + (size_t)j*16);
  }

  int wid = tid>>6, lane = tid&63;
  int wr = wid>>1, wc = wid&1;                 // wr 0..1 (4-row group), wc 0..1
  int col = lane&31, hi = lane>>5;
  int cob = (wc*64 + col)*128;                 // nf=0 W row base (bytes)

  f32x16 acc[4][2];
  #pragma unroll
  for(int a = 0; a < 4; ++a)
    #pragma unroll
    for(int b = 0; b < 2; ++b)
      #pragma unroll
      for(int r = 0; r < 16; ++r) acc[a][b][r] = 0.f;

  __syncthreads();

  for(int h = 0; h < 2; ++h){
    if(h == 1){
      // re-stage A with half 1 (all reads of half 0 drained by last barrier)
      #pragma unroll
      for(int it = 0; it < 12; ++it){
        int j = tid + it*256;
        int q9 = j/9;
        int s = j - 9*q9;
        int pidx = q9 > 339 ? 339 : q9;
        int ss = (s == 8) ? 0 : s;
        gload16(img + (size_t)pidx*256 + 128 + ss*16, Ab + (size_t)j*16);
      }
      __syncthreads();
    }
    for(int tap = 0; tap < 9; ++tap){
      int q = h*9 + tap;
      if(q < 17){
        const char* ws = wsrc + (size_t)(q+1)*16384;
        char* wdst = Wd + ((q+1)&1)*16384;
        #pragma unroll
        for(int it = 0; it < 4; ++it)
          gload16(ws + it*4096 + tid*16, wdst + it*4096 + tid*16);
      }
      const char* cur = Wd + (q&1)*16384;
      int dy = tap/3 - 1, dx = tap - (tap/3)*3 - 1;
      int pcol = col + 1 + dx;
      int prow0 = wr*4 + 1 + dy;                // tile-local padded row
      int a0b = (prow0*34 + pcol)*APITCH;
      int ka = 2*pcol;                          // additive A slot key (mod 8)
      __builtin_amdgcn_s_setprio(1);
      #pragma unroll
      for(int kc = 0; kc < 4; ++kc){
        int g = kc*2 + hi;                      // granule within half, 0..7
        int sa = ((g + ka)&7)<<4;
        bf16x8 af0 = *(const bf16x8*)(Ab + a0b + sa);
        bf16x8 af1 = *(const bf16x8*)(Ab + a0b + AROW + sa);
        bf16x8 af2 = *(const bf16x8*)(Ab + a0b + 2*AROW + sa);
        bf16x8 af3 = *(const bf16x8*)(Ab + a0b + 3*AROW + sa);
        int sw = ((g + 3*col)&7)<<4;
        bf16x8 wf0 = *(const bf16x8*)(cur + cob + sw);
        bf16x8 wf1 = *(const bf16x8*)(cur + cob + 4096 + sw);   // nf=1: +32co
        acc[0][0] = __builtin_amdgcn_mfma_f32_32x32x16_bf16(af0, wf0, acc[0][0], 0,0,0);
        acc[0][1] = __builtin_amdgcn_mfma_f32_32x32x16_bf16(af0, wf1, acc[0][1], 0,0,0);
        acc[1][0] = __builtin_amdgcn_mfma_f32_32x32x16_bf16(af1, wf0, acc[1][0], 0,0,0);
        acc[1][1] = __builtin_amdgcn_mfma_f32_32x32x16_bf16(af1, wf1, acc[1][1], 0,0,0);
        acc[2][0] = __builtin_amdgcn_mfma_f32_32x32x16_bf16(af2, wf0, acc[2][0], 0,0,0);
        acc[2][1] = __builtin_amdgcn_mfma_f32_32x32x16_bf16(af2, wf1, acc[2][1], 0,0,0);
        acc[3][0] = __builtin_amdgcn_mfma_f32_32x32x16_bf16(af3, wf0, acc[3][0], 0,0,0);
        acc[3][1] = __builtin_amdgcn_mfma_f32_32x32x16_bf16(af3, wf1, acc[3][1], 0,0,0);
      }
      __builtin_amdgcn_s_setprio(0);
      __syncthreads();   // reads of cur done + next W stage landed
    }
  }

  // epilogue: BN + relu -> LDS transpose scratch (reuse whole LDS), xnode regs
  char* eb = lds;
  float sn0 = 0.f, sn1 = 0.f;
  {
    const float rs = 0.9999950000374997f;
    float kb[2], ks[2], kbe[2];
    #pragma unroll
    for(int nf = 0; nf < 2; ++nf){
      int co = wc*64 + nf*32 + col;
      kb[nf] = bnb[co]; ks[nf] = bng[co]*rs; kbe[nf] = bnbe[co];
    }
    #pragma unroll
    for(int mi = 0; mi < 4; ++mi)
      #pragma unroll
      for(int reg = 0; reg < 16; ++reg){
        int pc = (reg&3) + 8*(reg>>2) + 4*hi;
        int px = (wr*4 + mi)*32 + pc;           // block-local 0..255
        #pragma unroll
        for(int nf = 0; nf < 2; ++nf){
          float v = (acc[mi][nf][reg] + kb[nf])*ks[nf] + kbe[nf];
          v = fmaxf(v, 0.f);
          if(nf == 0) sn0 += v; else sn1 += v;
          int co = wc*64 + nf*32 + col;
          *(unsigned short*)(eb + px*256 + ((co*2) ^ (((px>>2)&7)<<4))) = f2bf(v);
        }
      }
  }
  if(mode == 1){
    sn0 += __shfl_down(sn0, 32);
    sn1 += __shfl_down(sn1, 32);
    if(lane < 32){
      atomicAdd(&xnode_acc[n*HIDC + wc*64 + col], sn0);
      atomicAdd(&xnode_acc[n*HIDC + wc*64 + 32 + col], sn1);
    }
  }
  __syncthreads();
  {
    int p = tid;                                 // 0..255, 16 granules each
    int r = rg*8 + (p>>5), c = p&31;
    unsigned short* dst;
    int key;
    if(mode == 0){
      key = 2*((p&31) + 1);                     // padded additive key (mod 8)
      dst = outp + ((size_t)n*PPIX + (r+1)*PW2 + (c+1))*128;
    } else {
      key = 3*p;                                 // flat additive key (mod 8)
      dst = outp + ((size_t)n*HWPIX + rg*256 + p)*128;
    }
    #pragma unroll
    for(int s = 0; s < 16; ++s){
      uint4 v = *(uint4*)(eb + p*256 + ((s*16) ^ (((p>>2)&7)<<4)));
      int pos = (s>>3)*8 + (((s&7) + key)&7);
      *(uint4*)(dst + pos*8) = v;
    }
  }
}

// ---------------- GAT linear: h = x@lin, plus per-head attn dots ------------
__global__ void k_gat_lin(const float* __restrict__ xin, float scale,
                          const float* __restrict__ lin,
                          const float* __restrict__ as_, const float* __restrict__ ad_,
                          float* __restrict__ h, float* __restrict__ a_s, float* __restrict__ a_d){
  __shared__ float xs[128];
  __shared__ float rs0[4], rs1[4], rd0[4], rd1[4];
  int n = blockIdx.x, t = threadIdx.x;
  if(t < 128) xs[t] = xin[n*128 + t]*scale;
  __syncthreads();
  float o0 = 0.f, o1 = 0.f;
  for(int k = 0; k < 128; ++k){
    float xv = xs[k];
    o0 += xv*lin[k*512 + t];
    o1 += xv*lin[k*512 + t + 256];
  }
  h[(size_t)n*512 + t] = o0;
  h[(size_t)n*512 + t + 256] = o1;
  float s0 = o0*as_[t], s1 = o1*as_[t+256];
  float d0 = o0*ad_[t], d1 = o1*ad_[t+256];
  #pragma unroll
  for(int o = 32; o; o >>= 1){
    s0 += __shfl_down(s0, o); s1 += __shfl_down(s1, o);
    d0 += __shfl_down(d0, o); d1 += __shfl_down(d1, o);
  }
  int w = t>>6;
  if((t&63) == 0){ rs0[w]=s0; rs1[w]=s1; rd0[w]=d0; rd1[w]=d1; }
  __syncthreads();
  if(t < 4){
    if(t < 2){
      a_s[n*4+t] = rs0[2*t] + rs0[2*t+1];
      a_d[n*4+t] = rd0[2*t] + rd0[2*t+1];
    } else {
      a_s[n*4+t] = rs1[2*(t-2)] + rs1[2*(t-2)+1];
      a_d[n*4+t] = rd1[2*(t-2)] + rd1[2*(t-2)+1];
    }
  }
}

// ---------------- GAT aggregate: per-dst softmax + weighted sum -------------
__global__ void k_gat_aggr(const int* __restrict__ offs, const int* __restrict__ csr_src,
                           const float* __restrict__ a_s, const float* __restrict__ a_d,
                           const float* __restrict__ h, const float* __restrict__ bias,
                           float* __restrict__ y){
  __shared__ int ssrc[2048];
  __shared__ float sex[4][2048];
  __shared__ float out4[512];
  __shared__ float adn[4], smax[4], sden[4];
  __shared__ float wred[4][4];
  int n = blockIdx.x, t = threadIdx.x;
  int base = offs[n], deg = offs[n+1] - base;
  if(t < 4) adn[t] = a_d[n*4 + t];
  __syncthreads();
  bool cached = (deg <= 2048);
  float lm0=-1e30f, lm1=-1e30f, lm2=-1e30f, lm3=-1e30f;
  for(int e = t; e < deg; e += 256){
    int s = csr_src[base + e];
    float v0 = a_s[s*4+0] + adn[0]; v0 = v0 > 0.f ? v0 : 0.2f*v0;
    float v1 = a_s[s*4+1] + adn[1]; v1 = v1 > 0.f ? v1 : 0.2f*v1;
    float v2 = a_s[s*4+2] + adn[2]; v2 = v2 > 0.f ? v2 : 0.2f*v2;
    float v3 = a_s[s*4+3] + adn[3]; v3 = v3 > 0.f ? v3 : 0.2f*v3;
    if(cached){ ssrc[e]=s; sex[0][e]=v0; sex[1][e]=v1; sex[2][e]=v2; sex[3][e]=v3; }
    lm0 = fmaxf(lm0, v0); lm1 = fmaxf(lm1, v1); lm2 = fmaxf(lm2, v2); lm3 = fmaxf(lm3, v3);
  }
  #pragma unroll
  for(int o = 32; o; o >>= 1){
    lm0 = fmaxf(lm0, __shfl_down(lm0, o)); lm1 = fmaxf(lm1, __shfl_down(lm1, o));
    lm2 = fmaxf(lm2, __shfl_down(lm2, o)); lm3 = fmaxf(lm3, __shfl_down(lm3, o));
  }
  int w = t>>6;
  if((t&63) == 0){ wred[w][0]=lm0; wred[w][1]=lm1; wred[w][2]=lm2; wred[w][3]=lm3; }
  __syncthreads();
  if(t < 4) smax[t] = fmaxf(fmaxf(wred[0][t], wred[1][t]), fmaxf(wred[2][t], wred[3][t]));
  __syncthreads();
  float m0 = smax[0], m1 = smax[1], m2 = smax[2], m3 = smax[3];
  float ls0=0.f, ls1=0.f, ls2=0.f, ls3=0.f;
  for(int e = t; e < deg; e += 256){
    float e0, e1, e2, e3;
    if(cached){ e0 = sex[0][e]; e1 = sex[1][e]; e2 = sex[2][e]; e3 = sex[3][e]; }
    else {
      int s = csr_src[base + e];
      e0 = a_s[s*4+0] + adn[0]; e0 = e0 > 0.f ? e0 : 0.2f*e0;
      e1 = a_s[s*4+1] + adn[1]; e1 = e1 > 0.f ? e1 : 0.2f*e1;
      e2 = a_s[s*4+2] + adn[2]; e2 = e2 > 0.f ? e2 : 0.2f*e2;
      e3 = a_s[s*4+3] + adn[3]; e3 = e3 > 0.f ? e3 : 0.2f*e3;
    }
    e0 = __expf(e0-m0); e1 = __expf(e1-m1); e2 = __expf(e2-m2); e3 = __expf(e3-m3);
    if(cached){ sex[0][e]=e0; sex[1][e]=e1; sex[2][e]=e2; sex[3][e]=e3; }
    ls0 += e0; ls1 += e1; ls2 += e2; ls3 += e3;
  }
  #pragma unroll
  for(int o = 32; o; o >>= 1){
    ls0 += __shfl_down(ls0, o); ls1 += __shfl_down(ls1, o);
    ls2 += __shfl_down(ls2, o); ls3 += __shfl_down(ls3, o);
  }
  __syncthreads();   // wred(max) fully consumed
  if((t&63) == 0){ wred[w][0]=ls0; wred[w][1]=ls1; wred[w][2]=ls2; wred[w][3]=ls3; }
  __syncthreads();
  if(t < 4) sden[t] = wred[0][t] + wred[1][t] + wred[2][t] + wred[3][t] + 1e-16f;
  __syncthreads();
  #pragma unroll
  for(int oo = 0; oo < 2; ++oo){
    int o = t + oo*256;
    int hd = o>>7, d = o&127;
    float mh = smax[hd];
    float accv = 0.f;
    for(int e = 0; e < deg; ++e){
      float ex; int s;
      if(cached){ ex = sex[hd][e]; s = ssrc[e]; }
      else {
        s = csr_src[base + e];
        float v = a_s[s*4+hd] + adn[hd]; v = v > 0.f ? v : 0.2f*v;
        ex = __expf(v - mh);
      }
      accv += ex * h[(size_t)s*512 + hd*128 + d];
    }
    out4[o] = accv / sden[hd];
  }
  __syncthreads();
  if(t < 128){
    float v = (out4[t] + out4[128+t] + out4[256+t] + out4[384+t])*0.25f + bias[t];
    y[n*128 + t] = fmaxf(v, 0.f);
  }
}

// ---------------- per-node bias for final conv: nb = op_w @ xg2 + op_b ------
__global__ void k_nodebias(const float* __restrict__ xg2, const float* __restrict__ op_w,
                           const float* __restrict__ op_b, float* __restrict__ nb){
  int g = blockIdx.x*256 + threadIdx.x;
  if(g < NIMG*64){
    int n = g>>6, co = g&63;
    float acc = op_b[co];
    for(int k = 0; k < 128; ++k) acc += op_w[co*128+k]*xg2[n*128+k];
    nb[g] = acc;
  }
}

// ---------------- final 1x1 conv: out = op_w@xp2 + nb, NCHW f32 -------------
__launch_bounds__(256, 2)
__global__ void k_outconv(const unsigned short* __restrict__ xp2,  // flat, per-half pos=(g+3hw)&7
                          const unsigned short* __restrict__ Wop,
                          const float* __restrict__ nb, float* __restrict__ out){
  __shared__ char lds[16384];
  int tid = threadIdx.x;
  int n = blockIdx.x>>3, rg = blockIdx.x&7;
  #pragma unroll
  for(int it = 0; it < 4; ++it){
    uint4 v = *(const uint4*)((const char*)Wop + it*4096 + tid*16);
    *(uint4*)(lds + it*4096 + tid*16) = v;
  }
  __syncthreads();
  int wid = tid>>6, lane = tid&63;
  int wr = wid>>1, wc = wid&1, fr = lane&15, fq = lane>>4;
  f32x4 acc[4][2];
  #pragma unroll
  for(int a = 0; a < 4; ++a){ acc[a][0] = (f32x4){0.f,0.f,0.f,0.f}; acc[a][1] = (f32x4){0.f,0.f,0.f,0.f}; }
  const unsigned short* abase = xp2 + ((size_t)n*HWPIX + rg*128)*128;
  #pragma unroll
  for(int kc = 0; kc < 4; ++kc){
    bf16x8 af[4], bfr[2];
    #pragma unroll
    for(int mi = 0; mi < 4; ++mi){
      int p = wr*64 + mi*16 + fr;
      int G = kc*4 + fq;                       // semantic granule 0..15
      int pos = (G>>3)*8 + (((G&7) + 3*p)&7);
      af[mi] = *(const bf16x8*)(abase + p*128 + pos*8);
    }
    #pragma unroll
    for(int nf = 0; nf < 2; ++nf){
      int co = wc*32 + nf*16 + fr;
      int slot = (kc*4 + fq) ^ (co&7);
      bfr[nf] = *(const bf16x8*)(lds + co*256 + slot*16);
    }
    #pragma unroll
    for(int mi = 0; mi < 4; ++mi)
      #pragma unroll
      for(int nf = 0; nf < 2; ++nf)
        acc[mi][nf] = __builtin_amdgcn_mfma_f32_16x16x32_bf16(af[mi], bfr[nf], acc[mi][nf], 0,0,0);
  }
  #pragma unroll
  for(int mi = 0; mi < 4; ++mi)
    #pragma unroll
    for(int nf = 0; nf < 2; ++nf){
      int co = wc*32 + nf*16 + fr;
      int hw = rg*128 + wr*64 + mi*16 + fq*4;
      float nbv = nb[n*64 + co];
      float4 v = { acc[mi][nf][0]+nbv, acc[mi][nf][1]+nbv, acc[mi][nf][2]+nbv, acc[mi][nf][3]+nbv };
      *(float4*)(out + ((size_t)n*64 + co)*HWPIX + hw) = v;
    }
}

// ---------------- host launch ----------------------------------------------
extern "C" void kernel_launch(void* const* d_in, const int* in_sizes, int n_in,
                              void* d_out, int out_size, void* d_ws, size_t ws_size,
                              hipStream_t stream){
  const float* x       = (const float*)d_in[0];
  const int*   ei      = (const int*)d_in[1];
  const float* conf    = (const float*)d_in[2];
  const float* fe_w    = (const float*)d_in[3];
  const float* fe_b    = (const float*)d_in[4];
  const float* fe_g    = (const float*)d_in[5];
  const float* fe_beta = (const float*)d_in[6];
  const float* sp_w1   = (const float*)d_in[7];
  const float* sp_b1   = (const float*)d_in[8];
  const float* sp_g1   = (const float*)d_in[9];
  const float* sp_be1  = (const float*)d_in[10];
  const float* sp_w2   = (const float*)d_in[11];
  const float* sp_b2   = (const float*)d_in[12];
  const float* sp_g2   = (const float*)d_in[13];
  const float* sp_be2  = (const float*)d_in[14];
  const float* g1_lin  = (const float*)d_in[15];
  const float* g1_as   = (const float*)d_in[16];
  const float* g1_ad   = (const float*)d_in[17];
  const float* g1_b    = (const float*)d_in[18];
  const float* g2_lin  = (const float*)d_in[19];
  const float* g2_as   = (const float*)d_in[20];
  const float* g2_ad   = (const float*)d_in[21];
  const float* g2_b    = (const float*)d_in[22];
  const float* op_w    = (const float*)d_in[23];
  const float* op_b    = (const float*)d_in[24];
  float* out = (float*)d_out;

  char* ws = (char*)d_ws;
  size_t off = 0;
  auto alloc = [&](size_t bytes)->char*{
    char* p = ws + off; off += (bytes + 255) & ~(size_t)255; return p;
  };
  unsigned short* bigA  = (unsigned short*)alloc((size_t)NIMG*PPIX*128*2); // xe_pad, later xp2
  unsigned short* xp1   = (unsigned short*)alloc((size_t)NIMG*PPIX*128*2);
  unsigned short* Wb1   = (unsigned short*)alloc(147456*2);
  unsigned short* Wb2   = (unsigned short*)alloc(147456*2);
  unsigned short* Wfe   = (unsigned short*)alloc(8192*2);
  unsigned short* Wop   = (unsigned short*)alloc(8192*2);
  float* xnode_acc = (float*)alloc(NIMG*HIDC*4);
  float* h     = (float*)alloc((size_t)NIMG*512*4);
  float* a_s   = (float*)alloc(NIMG*4*4);
  float* a_d   = (float*)alloc(NIMG*4*4);
  float* xg1   = (float*)alloc(NIMG*HIDC*4);
  float* xg2   = (float*)alloc(NIMG*HIDC*4);
  int* cnt     = (int*)alloc(NIMG*4);
  int* pos     = (int*)alloc(NIMG*4);
  int* offs    = (int*)alloc((NIMG+1)*4);
  int* csr_src = (int*)alloc((NEDGE+NIMG)*4);
  float* nb    = (float*)alloc(NIMG*64*4);
  if(off > ws_size) return;   // workspace too small — bail cleanly
  unsigned short* xp2 = bigA; // reuse region A after conv1 consumed xe

  // 81920 B dynamic LDS for k_conv3 (A 49152 incl. gap + W dbuf 32768);
  // exactly 2 blocks/CU -> two independent barrier groups.
  hipFuncSetAttribute((const void*)k_conv3,
                      hipFuncAttributeMaxDynamicSharedMemorySize, 81920);

  k_init<<<1024, 256, 0, stream>>>(bigA, xp1, xnode_acc, cnt, pos);
  k_wconv<<<576, 256, 0, stream>>>(sp_w1, sp_w2, fe_w, op_w, Wb1, Wb2, Wfe, Wop);
  k_csr_count<<<(NEDGE+255)/256, 256, 0, stream>>>(ei, cnt);
  k_csr_scan<<<1, 512, 0, stream>>>(cnt, offs);
  k_csr_fill<<<(NEDGE+NIMG+255)/256, 256, 0, stream>>>(ei, offs, pos, csr_src);
  k_encode<<<4096, 256, 0, stream>>>(x, conf, Wfe, fe_b, fe_g, fe_beta, bigA);
  k_conv3<<<2048, 256, 81920, stream>>>(bigA, Wb1, sp_b1, sp_g1, sp_be1, xp1, xnode_acc, 0);
  k_conv3<<<2048, 256, 81920, stream>>>(xp1, Wb2, sp_b2, sp_g2, sp_be2, xp2, xnode_acc, 1);
  k_gat_lin<<<512, 256, 0, stream>>>(xnode_acc, 1.f/1024.f, g1_lin, g1_as, g1_ad, h, a_s, a_d);
  k_gat_aggr<<<512, 256, 0, stream>>>(offs, csr_src, a_s, a_d, h, g1_b, xg1);
  k_gat_lin<<<512, 256, 0, stream>>>(xg1, 1.f, g2_lin, g2_as, g2_ad, h, a_s, a_d);
  k_gat_aggr<<<512, 256, 0, stream>>>(offs, csr_src, a_s, a_d, h, g2_b, xg2);
  k_nodebias<<<(NIMG*64+255)/256, 256, 0, stream>>>(xg2, op_w, op_b, nb);
  k_outconv<<<4096, 256, 0, stream>>>(xp2, Wop, nb, out);
}

// Round 15
// 544.708 us; speedup vs baseline: 1.1467x; 1.0177x over previous
//
#include <hip/hip_runtime.h>
#include <stdint.h>

#define NIMG 512
#define CINCH 64
#define HIDC 128
#define NEDGE 16384
#define HWPIX 1024
#define PW2 34
#define PPIX 1156   // 34*34
#define APITCH 144  // LDS A-tile pixel pitch (8 granules + 1 dead)
#define AROW 4896   // 34*144

typedef __attribute__((ext_vector_type(8))) short bf16x8;
typedef __attribute__((ext_vector_type(4))) float f32x4;
typedef __attribute__((ext_vector_type(16))) float f32x16;

static __device__ __forceinline__ unsigned short f2bf(float f){
  unsigned u = __builtin_bit_cast(unsigned, f);
  u += 0x7FFFu + ((u>>16)&1u);
  return (unsigned short)(u>>16);
}
static __device__ __forceinline__ float bf2f(unsigned short s){
  unsigned u = ((unsigned)s)<<16;
  return __builtin_bit_cast(float, u);
}

// async 16B global->LDS, LDS side linear per wave (m104)
static __device__ __forceinline__ void gload16(const char* src, char* dst){
  __builtin_amdgcn_global_load_lds(
      (const __attribute__((address_space(1))) unsigned int*)src,
      (__attribute__((address_space(3))) unsigned int*)dst, 16, 0, 0);
}

// ---------------- init: zero pad borders + accumulators + csr counters ------
__global__ void k_init(unsigned short* xe_pad, unsigned short* xp1_pad,
                       float* xnode_acc, int* cnt, int* pos){
  int idx = blockIdx.x*256 + threadIdx.x;
  int total_b = NIMG*132*16;
  for(int i = idx; i < total_b; i += gridDim.x*256){
    int img = i / (132*16);
    int rem = i - img*(132*16);
    int bp = rem >> 4;
    int slot = rem & 15;
    int r, c;
    if(bp < 34){ r = 0; c = bp; }
    else if(bp < 68){ r = 33; c = bp-34; }
    else if(bp < 100){ r = bp-68+1; c = 0; }
    else { r = bp-100+1; c = 33; }
    size_t off = ((size_t)img*PPIX + r*PW2 + c)*128 + slot*8;
    uint4 z = {0,0,0,0};
    *(uint4*)(xe_pad + off) = z;
    *(uint4*)(xp1_pad + off) = z;
  }
  for(int i = idx; i < NIMG*HIDC; i += gridDim.x*256) xnode_acc[i] = 0.f;
  for(int i = idx; i < NIMG; i += gridDim.x*256){ cnt[i] = 0; pos[i] = 0; }
}

// ---------------- weight conversion ------------------------------------------
// conv3 W: 18 images of 16KB in STAGE ORDER img = h*9 + tap (matches q loop).
// Image layout [co][pos 0..7][8]; pos holds cin-group (pos-3co)&7 within half h.
__global__ void k_wconv(const float* __restrict__ sp_w1, const float* __restrict__ sp_w2,
                        const float* __restrict__ fe_w, const float* __restrict__ op_w,
                        unsigned short* Wb1, unsigned short* Wb2,
                        unsigned short* Wfe, unsigned short* Wop){
  int idx = blockIdx.x*256 + threadIdx.x;
  for(int i = idx; i < 147456; i += gridDim.x*256){
    int j = i & 7, pos = (i>>3)&7, co = (i>>6)&127, img = i>>13;  // img 0..17
    int h = img/9, tap = img - 9*h;
    int cin = h*64 + (((pos - 3*co) & 7)<<3) + j;
    Wb1[i] = f2bf(sp_w1[(co*128+cin)*9 + tap]);
    Wb2[i] = f2bf(sp_w2[(co*128+cin)*9 + tap]);
  }
  for(int i = idx; i < 8192; i += gridDim.x*256){
    int j = i & 7, s = (i>>3)&7, co = i>>6;
    int ci = ((s ^ (co&7))<<3) + j;
    Wfe[i] = f2bf(fe_w[co*64+ci]);
  }
  for(int i = idx; i < 8192; i += gridDim.x*256){
    int j = i & 7, s = (i>>3)&15, co = i>>7;   // co 0..63
    int cin = ((s ^ (co&7))<<3) + j;
    Wop[i] = f2bf(op_w[co*128+cin]);
  }
}

// ---------------- CSR build ------------------------------------------------
__global__ void k_csr_count(const int* __restrict__ ei, int* cnt){
  int e = blockIdx.x*256 + threadIdx.x;
  if(e < NEDGE) atomicAdd(&cnt[ei[NEDGE+e]], 1);
}
__global__ void k_csr_scan(const int* __restrict__ cnt, int* offs){
  __shared__ int sc[512];
  int t = threadIdx.x;
  sc[t] = cnt[t] + 1;   // +1 for self loop
  __syncthreads();
  for(int o = 1; o < 512; o <<= 1){
    int add = (t >= o) ? sc[t-o] : 0;
    __syncthreads();
    sc[t] += add;
    __syncthreads();
  }
  if(t == 0) offs[0] = 0;
  offs[t+1] = sc[t];
}
__global__ void k_csr_fill(const int* __restrict__ ei, const int* __restrict__ offs,
                           int* pos, int* csr_src){
  int e = blockIdx.x*256 + threadIdx.x;
  if(e < NEDGE + NIMG){
    int s, d;
    if(e < NEDGE){ s = ei[e]; d = ei[NEDGE+e]; }
    else { s = e - NEDGE; d = s; }
    int slot = offs[d] + atomicAdd(&pos[d], 1);
    csr_src[slot] = s;
  }
}

// ---------------- encode: 1x1 conv + BN + relu + conf, padded NHWC (baked) --
__launch_bounds__(256, 2)
__global__ void k_encode(const float* __restrict__ x, const float* __restrict__ conf,
                         const unsigned short* __restrict__ Wfe,
                         const float* __restrict__ fe_b, const float* __restrict__ fe_g,
                         const float* __restrict__ fe_beta,
                         unsigned short* __restrict__ xe_pad){
  __shared__ char lds[49152];          // xa 32KB (f32 swizzled) + wb 16KB
  char* xa = lds; char* wb = lds + 32768;
  int tid = threadIdx.x;
  int n = blockIdx.x >> 3, rg = blockIdx.x & 7;
  int hw0 = rg*128;
  {
    int q = tid >> 3, c0 = tid & 7;
    const float* xb = x + (size_t)n*CINCH*HWPIX + hw0;
    #pragma unroll
    for(int cc = 0; cc < 8; ++cc){
      int c = cc*8 + c0;
      float4 v = *(const float4*)(xb + (size_t)c*HWPIX + q*4);
      float vv[4] = {v.x, v.y, v.z, v.w};
      #pragma unroll
      for(int i = 0; i < 4; ++i){
        int p = q*4 + i;
        *(float*)(xa + p*256 + ((cc ^ (p&7))*32) + c0*4) = vv[i];
      }
    }
    #pragma unroll
    for(int it = 0; it < 4; ++it){
      uint4 w = *(const uint4*)((const char*)Wfe + it*4096 + tid*16);
      *(uint4*)(wb + it*4096 + tid*16) = w;
    }
  }
  __syncthreads();
  int wid = tid>>6, lane = tid&63;
  int wr = wid>>1, wc = wid&1, fr = lane&15, fq = lane>>4;
  f32x4 acc[4][4];
  #pragma unroll
  for(int a = 0; a < 4; ++a)
    #pragma unroll
    for(int b = 0; b < 4; ++b) acc[a][b] = (f32x4){0.f,0.f,0.f,0.f};
  #pragma unroll
  for(int kc = 0; kc < 2; ++kc){
    bf16x8 af[4], bfr[4];
    #pragma unroll
    for(int mi = 0; mi < 4; ++mi){
      int p = wr*64 + mi*16 + fr;
      int u = kc*4 + fq;
      const float* src = (const float*)(xa + p*256 + ((u ^ (p&7))*32));
      float4 lo = *(const float4*)src;
      float4 hi = *(const float4*)(src+4);
      bf16x8 a;
      a[0]=(short)f2bf(lo.x); a[1]=(short)f2bf(lo.y); a[2]=(short)f2bf(lo.z); a[3]=(short)f2bf(lo.w);
      a[4]=(short)f2bf(hi.x); a[5]=(short)f2bf(hi.y); a[6]=(short)f2bf(hi.z); a[7]=(short)f2bf(hi.w);
      af[mi] = a;
    }
    #pragma unroll
    for(int nf = 0; nf < 4; ++nf){
      int co = wc*64 + nf*16 + fr;
      int slot = (kc*4 + fq) ^ (co&7);
      bfr[nf] = *(const bf16x8*)(wb + co*128 + slot*16);
    }
    #pragma unroll
    for(int mi = 0; mi < 4; ++mi)
      #pragma unroll
      for(int nf = 0; nf < 4; ++nf)
        acc[mi][nf] = __builtin_amdgcn_mfma_f32_16x16x32_bf16(af[mi], bfr[nf], acc[mi][nf], 0,0,0);
  }
  __syncthreads();
  {
    const float rs = 0.9999950000374997f;
    float kb[4], ks[4], kbe[4];
    #pragma unroll
    for(int nf = 0; nf < 4; ++nf){
      int co = wc*64 + nf*16 + fr;
      kb[nf] = fe_b[co]; ks[nf] = fe_g[co]*rs; kbe[nf] = fe_beta[co];
    }
    #pragma unroll
    for(int mi = 0; mi < 4; ++mi)
      #pragma unroll
      for(int j = 0; j < 4; ++j){
        int px = wr*64 + mi*16 + fq*4 + j;
        float cf = conf[(size_t)n*HWPIX + hw0 + px];
        #pragma unroll
        for(int nf = 0; nf < 4; ++nf){
          float v = (acc[mi][nf][j] + kb[nf])*ks[nf] + kbe[nf];
          v = fmaxf(v, 0.f)*cf;
          int co = wc*64 + nf*16 + fr;
          *(unsigned short*)(xa + px*256 + ((co*2) ^ (((px>>2)&7)<<4))) = f2bf(v);
        }
      }
  }
  __syncthreads();
  {
    int p = tid>>1, half = tid&1;
    int r = rg*4 + (p>>5), c = p&31;
    int key = 2*((p&31) + 1);                // additive key, padded col (mod 8)
    unsigned short* dst = xe_pad + ((size_t)n*PPIX + (r+1)*PW2 + (c+1))*128;
    #pragma unroll
    for(int s = 0; s < 8; ++s){
      int ls = half*8 + s;                   // semantic granule 0..15
      uint4 v = *(uint4*)(xa + p*256 + ((ls*16) ^ (((p>>2)&7)<<4)));
      int pos = (ls>>3)*8 + (((ls&7) + key)&7);
      *(uint4*)(dst + pos*8) = v;
    }
  }
}

// ---------------- 3x3 conv: K-split, 256 thr / 4 waves, 2 blocks/CU ---------
// Block tile 8 rows x 128 co; K in two 64-ch halves (A half-tile re-staged at
// h switch). Wave tile 128px x 64co, acc f32x16[4][2]. LDS = A 340px x 144B
// (+192B gap) + W dbuf 2x16KB = 81920B exactly -> 2 independent barrier
// groups per CU. Epilogue store: 2 lanes per pixel x 2 pixel-blocks.
__launch_bounds__(256, 2)
__global__ void k_conv3(const unsigned short* __restrict__ inp,   // padded, baked
                        const unsigned short* __restrict__ Wb,    // [h*9+tap][128][8][8]
                        const float* __restrict__ bnb, const float* __restrict__ bng,
                        const float* __restrict__ bnbe,
                        unsigned short* __restrict__ outp,
                        float* __restrict__ xnode_acc, int mode){
  extern __shared__ char lds[];
  char* Ab = lds;                 // 48960 used + 192 gap (clamped dup-loads)
  char* Wd = lds + 49152;         // 2 x 16384
  int tid = threadIdx.x;
  int n = blockIdx.x>>2, rg = blockIdx.x&3;

  const char* img  = (const char*)inp + ((size_t)n*PPIX + (size_t)rg*8*PW2)*256;
  const char* wsrc = (const char*)Wb;

  // prologue: W(q=0) + A(h=0); all lanes of all waves active, linear LDS dst
  #pragma unroll
  for(int it = 0; it < 4; ++it)
    gload16(wsrc + it*4096 + tid*16, Wd + it*4096 + tid*16);
  #pragma unroll
  for(int it = 0; it < 12; ++it){
    int j = tid + it*256;             // 0..3071 (3060 real, rest clamped dup)
    int q9 = j/9;
    int s = j - 9*q9;                  // 0..8
    int pidx = q9 > 339 ? 339 : q9;
    int ss = (s == 8) ? 0 : s;
    gload16(img + (size_t)pidx*256 + 0*128 + ss*16, Ab + (size_t)j*16);
  }

  int wid = tid>>6, lane = tid&63;
  int wr = wid>>1, wc = wid&1;                 // wr 0..1 (4-row group), wc 0..1
  int col = lane&31, hi = lane>>5;
  int cob = (wc*64 + col)*128;                 // nf=0 W row base (bytes)

  f32x16 acc[4][2];
  #pragma unroll
  for(int a = 0; a < 4; ++a)
    #pragma unroll
    for(int b = 0; b < 2; ++b)
      #pragma unroll
      for(int r = 0; r < 16; ++r) acc[a][b][r] = 0.f;

  __syncthreads();

  for(int h = 0; h < 2; ++h){
    if(h == 1){
      // re-stage A with half 1 (all reads of half 0 drained by last barrier)
      #pragma unroll
      for(int it = 0; it < 12; ++it){
        int j = tid + it*256;
        int q9 = j/9;
        int s = j - 9*q9;
        int pidx = q9 > 339 ? 339 : q9;
        int ss = (s == 8) ? 0 : s;
        gload16(img + (size_t)pidx*256 + 128 + ss*16, Ab + (size_t)j*16);
      }
      __syncthreads();
    }
    for(int tap = 0; tap < 9; ++tap){
      int q = h*9 + tap;
      if(q < 17){
        const char* ws = wsrc + (size_t)(q+1)*16384;
        char* wdst = Wd + ((q+1)&1)*16384;
        #pragma unroll
        for(int it = 0; it < 4; ++it)
          gload16(ws + it*4096 + tid*16, wdst + it*4096 + tid*16);
      }
      const char* cur = Wd + (q&1)*16384;
      int dy = tap/3 - 1, dx = tap - (tap/3)*3 - 1;
      int pcol = col + 1 + dx;
      int prow0 = wr*4 + 1 + dy;                // tile-local padded row
      int a0b = (prow0*34 + pcol)*APITCH;
      int ka = 2*pcol;                          // additive A slot key (mod 8)
      __builtin_amdgcn_s_setprio(1);
      #pragma unroll
      for(int kc = 0; kc < 4; ++kc){
        int g = kc*2 + hi;                      // granule within half, 0..7
        int sa = ((g + ka)&7)<<4;
        bf16x8 af0 = *(const bf16x8*)(Ab + a0b + sa);
        bf16x8 af1 = *(const bf16x8*)(Ab + a0b + AROW + sa);
        bf16x8 af2 = *(const bf16x8*)(Ab + a0b + 2*AROW + sa);
        bf16x8 af3 = *(const bf16x8*)(Ab + a0b + 3*AROW + sa);
        int sw = ((g + 3*col)&7)<<4;
        bf16x8 wf0 = *(const bf16x8*)(cur + cob + sw);
        bf16x8 wf1 = *(const bf16x8*)(cur + cob + 4096 + sw);   // nf=1: +32co
        acc[0][0] = __builtin_amdgcn_mfma_f32_32x32x16_bf16(af0, wf0, acc[0][0], 0,0,0);
        acc[0][1] = __builtin_amdgcn_mfma_f32_32x32x16_bf16(af0, wf1, acc[0][1], 0,0,0);
        acc[1][0] = __builtin_amdgcn_mfma_f32_32x32x16_bf16(af1, wf0, acc[1][0], 0,0,0);
        acc[1][1] = __builtin_amdgcn_mfma_f32_32x32x16_bf16(af1, wf1, acc[1][1], 0,0,0);
        acc[2][0] = __builtin_amdgcn_mfma_f32_32x32x16_bf16(af2, wf0, acc[2][0], 0,0,0);
        acc[2][1] = __builtin_amdgcn_mfma_f32_32x32x16_bf16(af2, wf1, acc[2][1], 0,0,0);
        acc[3][0] = __builtin_amdgcn_mfma_f32_32x32x16_bf16(af3, wf0, acc[3][0], 0,0,0);
        acc[3][1] = __builtin_amdgcn_mfma_f32_32x32x16_bf16(af3, wf1, acc[3][1], 0,0,0);
      }
      __builtin_amdgcn_s_setprio(0);
      __syncthreads();   // reads of cur done + next W stage landed
    }
  }

  // epilogue: BN + relu -> LDS transpose scratch (reuse whole LDS), xnode regs
  char* eb = lds;
  float sn0 = 0.f, sn1 = 0.f;
  {
    const float rs = 0.9999950000374997f;
    float kb[2], ks[2], kbe[2];
    #pragma unroll
    for(int nf = 0; nf < 2; ++nf){
      int co = wc*64 + nf*32 + col;
      kb[nf] = bnb[co]; ks[nf] = bng[co]*rs; kbe[nf] = bnbe[co];
    }
    #pragma unroll
    for(int mi = 0; mi < 4; ++mi)
      #pragma unroll
      for(int reg = 0; reg < 16; ++reg){
        int pc = (reg&3) + 8*(reg>>2) + 4*hi;
        int px = (wr*4 + mi)*32 + pc;           // block-local 0..255
        #pragma unroll
        for(int nf = 0; nf < 2; ++nf){
          float v = (acc[mi][nf][reg] + kb[nf])*ks[nf] + kbe[nf];
          v = fmaxf(v, 0.f);
          if(nf == 0) sn0 += v; else sn1 += v;
          int co = wc*64 + nf*32 + col;
          *(unsigned short*)(eb + px*256 + ((co*2) ^ (((px>>2)&7)<<4))) = f2bf(v);
        }
      }
  }
  if(mode == 1){
    sn0 += __shfl_down(sn0, 32);
    sn1 += __shfl_down(sn1, 32);
    if(lane < 32){
      atomicAdd(&xnode_acc[n*HIDC + wc*64 + col], sn0);
      atomicAdd(&xnode_acc[n*HIDC + wc*64 + 32 + col], sn1);
    }
  }
  __syncthreads();
  {
    int half = tid&1;
    #pragma unroll
    for(int pb = 0; pb < 2; ++pb){
      int p = (tid>>1) + pb*128;                // 2 lanes per pixel, 2 pixels
      int r = rg*8 + (p>>5), c = p&31;
      unsigned short* dst;
      int key;
      if(mode == 0){
        key = 2*((p&31) + 1);                   // padded additive key (mod 8)
        dst = outp + ((size_t)n*PPIX + (r+1)*PW2 + (c+1))*128;
      } else {
        key = 3*p;                               // flat additive key (mod 8)
        dst = outp + ((size_t)n*HWPIX + rg*256 + p)*128;
      }
      #pragma unroll
      for(int s = 0; s < 8; ++s){
        int ls = half*8 + s;                    // semantic granule 0..15
        uint4 v = *(uint4*)(eb + p*256 + ((ls*16) ^ (((p>>2)&7)<<4)));
        int pos = (ls>>3)*8 + (((ls&7) + key)&7);
        *(uint4*)(dst + pos*8) = v;
      }
    }
  }
}

// ---------------- GAT linear: h = x@lin, plus per-head attn dots ------------
__global__ void k_gat_lin(const float* __restrict__ xin, float scale,
                          const float* __restrict__ lin,
                          const float* __restrict__ as_, const float* __restrict__ ad_,
                          float* __restrict__ h, float* __restrict__ a_s, float* __restrict__ a_d){
  __shared__ float xs[128];
  __shared__ float rs0[4], rs1[4], rd0[4], rd1[4];
  int n = blockIdx.x, t = threadIdx.x;
  if(t < 128) xs[t] = xin[n*128 + t]*scale;
  __syncthreads();
  float o0 = 0.f, o1 = 0.f;
  for(int k = 0; k < 128; ++k){
    float xv = xs[k];
    o0 += xv*lin[k*512 + t];
    o1 += xv*lin[k*512 + t + 256];
  }
  h[(size_t)n*512 + t] = o0;
  h[(size_t)n*512 + t + 256] = o1;
  float s0 = o0*as_[t], s1 = o1*as_[t+256];
  float d0 = o0*ad_[t], d1 = o1*ad_[t+256];
  #pragma unroll
  for(int o = 32; o; o >>= 1){
    s0 += __shfl_down(s0, o); s1 += __shfl_down(s1, o);
    d0 += __shfl_down(d0, o); d1 += __shfl_down(d1, o);
  }
  int w = t>>6;
  if((t&63) == 0){ rs0[w]=s0; rs1[w]=s1; rd0[w]=d0; rd1[w]=d1; }
  __syncthreads();
  if(t < 4){
    if(t < 2){
      a_s[n*4+t] = rs0[2*t] + rs0[2*t+1];
      a_d[n*4+t] = rd0[2*t] + rd0[2*t+1];
    } else {
      a_s[n*4+t] = rs1[2*(t-2)] + rs1[2*(t-2)+1];
      a_d[n*4+t] = rd1[2*(t-2)] + rd1[2*(t-2)+1];
    }
  }
}

// ---------------- GAT aggregate: per-dst softmax + weighted sum -------------
__global__ void k_gat_aggr(const int* __restrict__ offs, const int* __restrict__ csr_src,
                           const float* __restrict__ a_s, const float* __restrict__ a_d,
                           const float* __restrict__ h, const float* __restrict__ bias,
                           float* __restrict__ y){
  __shared__ int ssrc[2048];
  __shared__ float sex[4][2048];
  __shared__ float out4[512];
  __shared__ float adn[4], smax[4], sden[4];
  __shared__ float wred[4][4];
  int n = blockIdx.x, t = threadIdx.x;
  int base = offs[n], deg = offs[n+1] - base;
  if(t < 4) adn[t] = a_d[n*4 + t];
  __syncthreads();
  bool cached = (deg <= 2048);
  float lm0=-1e30f, lm1=-1e30f, lm2=-1e30f, lm3=-1e30f;
  for(int e = t; e < deg; e += 256){
    int s = csr_src[base + e];
    float v0 = a_s[s*4+0] + adn[0]; v0 = v0 > 0.f ? v0 : 0.2f*v0;
    float v1 = a_s[s*4+1] + adn[1]; v1 = v1 > 0.f ? v1 : 0.2f*v1;
    float v2 = a_s[s*4+2] + adn[2]; v2 = v2 > 0.f ? v2 : 0.2f*v2;
    float v3 = a_s[s*4+3] + adn[3]; v3 = v3 > 0.f ? v3 : 0.2f*v3;
    if(cached){ ssrc[e]=s; sex[0][e]=v0; sex[1][e]=v1; sex[2][e]=v2; sex[3][e]=v3; }
    lm0 = fmaxf(lm0, v0); lm1 = fmaxf(lm1, v1); lm2 = fmaxf(lm2, v2); lm3 = fmaxf(lm3, v3);
  }
  #pragma unroll
  for(int o = 32; o; o >>= 1){
    lm0 = fmaxf(lm0, __shfl_down(lm0, o)); lm1 = fmaxf(lm1, __shfl_down(lm1, o));
    lm2 = fmaxf(lm2, __shfl_down(lm2, o)); lm3 = fmaxf(lm3, __shfl_down(lm3, o));
  }
  int w = t>>6;
  if((t&63) == 0){ wred[w][0]=lm0; wred[w][1]=lm1; wred[w][2]=lm2; wred[w][3]=lm3; }
  __syncthreads();
  if(t < 4) smax[t] = fmaxf(fmaxf(wred[0][t], wred[1][t]), fmaxf(wred[2][t], wred[3][t]));
  __syncthreads();
  float m0 = smax[0], m1 = smax[1], m2 = smax[2], m3 = smax[3];
  float ls0=0.f, ls1=0.f, ls2=0.f, ls3=0.f;
  for(int e = t; e < deg; e += 256){
    float e0, e1, e2, e3;
    if(cached){ e0 = sex[0][e]; e1 = sex[1][e]; e2 = sex[2][e]; e3 = sex[3][e]; }
    else {
      int s = csr_src[base + e];
      e0 = a_s[s*4+0] + adn[0]; e0 = e0 > 0.f ? e0 : 0.2f*e0;
      e1 = a_s[s*4+1] + adn[1]; e1 = e1 > 0.f ? e1 : 0.2f*e1;
      e2 = a_s[s*4+2] + adn[2]; e2 = e2 > 0.f ? e2 : 0.2f*e2;
      e3 = a_s[s*4+3] + adn[3]; e3 = e3 > 0.f ? e3 : 0.2f*e3;
    }
    e0 = __expf(e0-m0); e1 = __expf(e1-m1); e2 = __expf(e2-m2); e3 = __expf(e3-m3);
    if(cached){ sex[0][e]=e0; sex[1][e]=e1; sex[2][e]=e2; sex[3][e]=e3; }
    ls0 += e0; ls1 += e1; ls2 += e2; ls3 += e3;
  }
  #pragma unroll
  for(int o = 32; o; o >>= 1){
    ls0 += __shfl_down(ls0, o); ls1 += __shfl_down(ls1, o);
    ls2 += __shfl_down(ls2, o); ls3 += __shfl_down(ls3, o);
  }
  __syncthreads();   // wred(max) fully consumed
  if((t&63) == 0){ wred[w][0]=ls0; wred[w][1]=ls1; wred[w][2]=ls2; wred[w][3]=ls3; }
  __syncthreads();
  if(t < 4) sden[t] = wred[0][t] + wred[1][t] + wred[2][t] + wred[3][t] + 1e-16f;
  __syncthreads();
  #pragma unroll
  for(int oo = 0; oo < 2; ++oo){
    int o = t + oo*256;
    int hd = o>>7, d = o&127;
    float mh = smax[hd];
    float accv = 0.f;
    for(int e = 0; e < deg; ++e){
      float ex; int s;
      if(cached){ ex = sex[hd][e]; s = ssrc[e]; }
      else {
        s = csr_src[base + e];
        float v = a_s[s*4+hd] + adn[hd]; v = v > 0.f ? v : 0.2f*v;
        ex = __expf(v - mh);
      }
      accv += ex * h[(size_t)s*512 + hd*128 + d];
    }
    out4[o] = accv / sden[hd];
  }
  __syncthreads();
  if(t < 128){
    float v = (out4[t] + out4[128+t] + out4[256+t] + out4[384+t])*0.25f + bias[t];
    y[n*128 + t] = fmaxf(v, 0.f);
  }
}

// ---------------- per-node bias for final conv: nb = op_w @ xg2 + op_b ------
__global__ void k_nodebias(const float* __restrict__ xg2, const float* __restrict__ op_w,
                           const float* __restrict__ op_b, float* __restrict__ nb){
  int g = blockIdx.x*256 + threadIdx.x;
  if(g < NIMG*64){
    int n = g>>6, co = g&63;
    float acc = op_b[co];
    for(int k = 0; k < 128; ++k) acc += op_w[co*128+k]*xg2[n*128+k];
    nb[g] = acc;
  }
}

// ---------------- final 1x1 conv: out = op_w@xp2 + nb, NCHW f32 -------------
__launch_bounds__(256, 2)
__global__ void k_outconv(const unsigned short* __restrict__ xp2,  // flat, per-half pos=(g+3hw)&7
                          const unsigned short* __restrict__ Wop,
                          const float* __restrict__ nb, float* __restrict__ out){
  __shared__ char lds[16384];
  int tid = threadIdx.x;
  int n = blockIdx.x>>3, rg = blockIdx.x&7;
  #pragma unroll
  for(int it = 0; it < 4; ++it){
    uint4 v = *(const uint4*)((const char*)Wop + it*4096 + tid*16);
    *(uint4*)(lds + it*4096 + tid*16) = v;
  }
  __syncthreads();
  int wid = tid>>6, lane = tid&63;
  int wr = wid>>1, wc = wid&1, fr = lane&15, fq = lane>>4;
  f32x4 acc[4][2];
  #pragma unroll
  for(int a = 0; a < 4; ++a){ acc[a][0] = (f32x4){0.f,0.f,0.f,0.f}; acc[a][1] = (f32x4){0.f,0.f,0.f,0.f}; }
  const unsigned short* abase = xp2 + ((size_t)n*HWPIX + rg*128)*128;
  #pragma unroll
  for(int kc = 0; kc < 4; ++kc){
    bf16x8 af[4], bfr[2];
    #pragma unroll
    for(int mi = 0; mi < 4; ++mi){
      int p = wr*64 + mi*16 + fr;
      int G = kc*4 + fq;                       // semantic granule 0..15
      int pos = (G>>3)*8 + (((G&7) + 3*p)&7);
      af[mi] = *(const bf16x8*)(abase + p*128 + pos*8);
    }
    #pragma unroll
    for(int nf = 0; nf < 2; ++nf){
      int co = wc*32 + nf*16 + fr;
      int slot = (kc*4 + fq) ^ (co&7);
      bfr[nf] = *(const bf16x8*)(lds + co*256 + slot*16);
    }
    #pragma unroll
    for(int mi = 0; mi < 4; ++mi)
      #pragma unroll
      for(int nf = 0; nf < 2; ++nf)
        acc[mi][nf] = __builtin_amdgcn_mfma_f32_16x16x32_bf16(af[mi], bfr[nf], acc[mi][nf], 0,0,0);
  }
  #pragma unroll
  for(int mi = 0; mi < 4; ++mi)
    #pragma unroll
    for(int nf = 0; nf < 2; ++nf){
      int co = wc*32 + nf*16 + fr;
      int hw = rg*128 + wr*64 + mi*16 + fq*4;
      float nbv = nb[n*64 + co];
      float4 v = { acc[mi][nf][0]+nbv, acc[mi][nf][1]+nbv, acc[mi][nf][2]+nbv, acc[mi][nf][3]+nbv };
      *(float4*)(out + ((size_t)n*64 + co)*HWPIX + hw) = v;
    }
}

// ---------------- host launch ----------------------------------------------
extern "C" void kernel_launch(void* const* d_in, const int* in_sizes, int n_in,
                              void* d_out, int out_size, void* d_ws, size_t ws_size,
                              hipStream_t stream){
  const float* x       = (const float*)d_in[0];
  const int*   ei      = (const int*)d_in[1];
  const float* conf    = (const float*)d_in[2];
  const float* fe_w    = (const float*)d_in[3];
  const float* fe_b    = (const float*)d_in[4];
  const float* fe_g    = (const float*)d_in[5];
  const float* fe_beta = (const float*)d_in[6];
  const float* sp_w1   = (const float*)d_in[7];
  const float* sp_b1   = (const float*)d_in[8];
  const float* sp_g1   = (const float*)d_in[9];
  const float* sp_be1  = (const float*)d_in[10];
  const float* sp_w2   = (const float*)d_in[11];
  const float* sp_b2   = (const float*)d_in[12];
  const float* sp_g2   = (const float*)d_in[13];
  const float* sp_be2  = (const float*)d_in[14];
  const float* g1_lin  = (const float*)d_in[15];
  const float* g1_as   = (const float*)d_in[16];
  const float* g1_ad   = (const float*)d_in[17];
  const float* g1_b    = (const float*)d_in[18];
  const float* g2_lin  = (const float*)d_in[19];
  const float* g2_as   = (const float*)d_in[20];
  const float* g2_ad   = (const float*)d_in[21];
  const float* g2_b    = (const float*)d_in[22];
  const float* op_w    = (const float*)d_in[23];
  const float* op_b    = (const float*)d_in[24];
  float* out = (float*)d_out;

  char* ws = (char*)d_ws;
  size_t off = 0;
  auto alloc = [&](size_t bytes)->char*{
    char* p = ws + off; off += (bytes + 255) & ~(size_t)255; return p;
  };
  unsigned short* bigA  = (unsigned short*)alloc((size_t)NIMG*PPIX*128*2); // xe_pad, later xp2
  unsigned short* xp1   = (unsigned short*)alloc((size_t)NIMG*PPIX*128*2);
  unsigned short* Wb1   = (unsigned short*)alloc(147456*2);
  unsigned short* Wb2   = (unsigned short*)alloc(147456*2);
  unsigned short* Wfe   = (unsigned short*)alloc(8192*2);
  unsigned short* Wop   = (unsigned short*)alloc(8192*2);
  float* xnode_acc = (float*)alloc(NIMG*HIDC*4);
  float* h     = (float*)alloc((size_t)NIMG*512*4);
  float* a_s   = (float*)alloc(NIMG*4*4);
  float* a_d   = (float*)alloc(NIMG*4*4);
  float* xg1   = (float*)alloc(NIMG*HIDC*4);
  float* xg2   = (float*)alloc(NIMG*HIDC*4);
  int* cnt     = (int*)alloc(NIMG*4);
  int* pos     = (int*)alloc(NIMG*4);
  int* offs    = (int*)alloc((NIMG+1)*4);
  int* csr_src = (int*)alloc((NEDGE+NIMG)*4);
  float* nb    = (float*)alloc(NIMG*64*4);
  if(off > ws_size) return;   // workspace too small — bail cleanly
  unsigned short* xp2 = bigA; // reuse region A after conv1 consumed xe

  // 81920 B dynamic LDS for k_conv3 (A 49152 incl. gap + W dbuf 32768);
  // exactly 2 blocks/CU -> two independent barrier groups.
  hipFuncSetAttribute((const void*)k_conv3,
                      hipFuncAttributeMaxDynamicSharedMemorySize, 81920);

  k_init<<<1024, 256, 0, stream>>>(bigA, xp1, xnode_acc, cnt, pos);
  k_wconv<<<576, 256, 0, stream>>>(sp_w1, sp_w2, fe_w, op_w, Wb1, Wb2, Wfe, Wop);
  k_csr_count<<<(NEDGE+255)/256, 256, 0, stream>>>(ei, cnt);
  k_csr_scan<<<1, 512, 0, stream>>>(cnt, offs);
  k_csr_fill<<<(NEDGE+NIMG+255)/256, 256, 0, stream>>>(ei, offs, pos, csr_src);
  k_encode<<<4096, 256, 0, stream>>>(x, conf, Wfe, fe_b, fe_g, fe_beta, bigA);
  k_conv3<<<2048, 256, 81920, stream>>>(bigA, Wb1, sp_b1, sp_g1, sp_be1, xp1, xnode_acc, 0);
  k_conv3<<<2048, 256, 81920, stream>>>(xp1, Wb2, sp_b2, sp_g2, sp_be2, xp2, xnode_acc, 1);
  k_gat_lin<<<512, 256, 0, stream>>>(xnode_acc, 1.f/1024.f, g1_lin, g1_as, g1_ad, h, a_s, a_d);
  k_gat_aggr<<<512, 256, 0, stream>>>(offs, csr_src, a_s, a_d, h, g1_b, xg1);
  k_gat_lin<<<512, 256, 0, stream>>>(xg1, 1.f, g2_lin, g2_as, g2_ad, h, a_s, a_d);
  k_gat_aggr<<<512, 256, 0, stream>>>(offs, csr_src, a_s, a_d, h, g2_b, xg2);
  k_nodebias<<<(NIMG*64+255)/256, 256, 0, stream>>>(xg2, op_w, op_b, nb);
  k_outconv<<<4096, 256, 0, stream>>>(xp2, Wop, nb, out);
}